// Round 1
// baseline (1432.696 us; speedup 1.0000x reference)
//
#include <hip/hip_runtime.h>
#include <hip/hip_bf16.h>
#include <math.h>

#define N_NODES 50000
#define E_EDGES 800000
#define NEG_SLOPE 0.2f
#define EPS 1e-16f

// ---------------------------------------------------------------------------
// Tiled fp32 GEMM: Y[N,M] = X[N,K] @ W[K,M].  64x64 tile, 256 threads, 4x4
// micro-tile per thread. K, M multiples of 64. As padded +1 to kill bank
// conflicts; Bs read as float4 (ds_read_b128).
// ---------------------------------------------------------------------------
__global__ __launch_bounds__(256)
void gemm64(const float* __restrict__ X, const float* __restrict__ W,
            float* __restrict__ Y, int Nrows, int K, int M)
{
    __shared__ float As[64][65];
    __shared__ float Bs[64][64];
    const int tid = threadIdx.x;
    const int tx = tid & 15;          // 0..15  (col group)
    const int ty = tid >> 4;          // 0..15  (row group)
    const int row0 = blockIdx.y * 64;
    const int col0 = blockIdx.x * 64;

    float acc[4][4] = {};

    for (int k0 = 0; k0 < K; k0 += 64) {
        #pragma unroll
        for (int i = 0; i < 4; ++i) {
            const int r = (tid >> 4) + i * 16;
            const int c = (tid & 15) * 4;
            const int gr = row0 + r;
            float4 v = make_float4(0.f, 0.f, 0.f, 0.f);
            if (gr < Nrows)
                v = *(const float4*)(X + (size_t)gr * K + k0 + c);
            As[r][c + 0] = v.x; As[r][c + 1] = v.y;
            As[r][c + 2] = v.z; As[r][c + 3] = v.w;
            const float4 w = *(const float4*)(W + (size_t)(k0 + r) * M + col0 + c);
            *(float4*)&Bs[r][c] = w;
        }
        __syncthreads();

        #pragma unroll
        for (int k = 0; k < 64; ++k) {
            const float4 b = *(float4*)&Bs[k][tx * 4];
            const float a0 = As[ty * 4 + 0][k];
            const float a1 = As[ty * 4 + 1][k];
            const float a2 = As[ty * 4 + 2][k];
            const float a3 = As[ty * 4 + 3][k];
            acc[0][0] += a0 * b.x; acc[0][1] += a0 * b.y; acc[0][2] += a0 * b.z; acc[0][3] += a0 * b.w;
            acc[1][0] += a1 * b.x; acc[1][1] += a1 * b.y; acc[1][2] += a1 * b.z; acc[1][3] += a1 * b.w;
            acc[2][0] += a2 * b.x; acc[2][1] += a2 * b.y; acc[2][2] += a2 * b.z; acc[2][3] += a2 * b.w;
            acc[3][0] += a3 * b.x; acc[3][1] += a3 * b.y; acc[3][2] += a3 * b.z; acc[3][3] += a3 * b.w;
        }
        __syncthreads();
    }

    #pragma unroll
    for (int i = 0; i < 4; ++i) {
        const int gr = row0 + ty * 4 + i;
        if (gr < Nrows) {
            float4 v = make_float4(acc[i][0], acc[i][1], acc[i][2], acc[i][3]);
            *(float4*)(Y + (size_t)gr * M + col0 + tx * 4) = v;
        }
    }
}

// ---------------------------------------------------------------------------
// Layer-1 edge pass (H=4, C=64): one wave per edge (grid-stride).
// Lane l owns channel h*64+l for h=0..3. Computes per-head score
// ee_h = exp(sum_c leaky(xl+xr)*att) (no max-subtraction: scores are O(1);
// ratio is mathematically identical), then atomically accumulates
// ee_h * xl[src] into acc and ee_h into denom.
// ---------------------------------------------------------------------------
__global__ __launch_bounds__(256)
void edge1(const float* __restrict__ xl, const float* __restrict__ xr,
           const int* __restrict__ src, const int* __restrict__ dst,
           const float* __restrict__ att,
           float* __restrict__ acc, float* __restrict__ denom, int E)
{
    const int lane = threadIdx.x & 63;
    int w = (blockIdx.x * blockDim.x + threadIdx.x) >> 6;
    const int nw = (gridDim.x * blockDim.x) >> 6;
    const float at0 = att[lane];
    const float at1 = att[64 + lane];
    const float at2 = att[128 + lane];
    const float at3 = att[192 + lane];

    for (int e = w; e < E; e += nw) {
        const int s = src[e];
        const int d = dst[e];
        const float* pl = xl + (size_t)s * 256;
        const float* pr = xr + (size_t)d * 256;
        const float l0 = pl[lane];        const float r0 = pr[lane];
        const float l1 = pl[64 + lane];   const float r1 = pr[64 + lane];
        const float l2 = pl[128 + lane];  const float r2 = pr[128 + lane];
        const float l3 = pl[192 + lane];  const float r3 = pr[192 + lane];

        float m0 = l0 + r0; m0 = (m0 > 0.f ? m0 : NEG_SLOPE * m0) * at0;
        float m1 = l1 + r1; m1 = (m1 > 0.f ? m1 : NEG_SLOPE * m1) * at1;
        float m2 = l2 + r2; m2 = (m2 > 0.f ? m2 : NEG_SLOPE * m2) * at2;
        float m3 = l3 + r3; m3 = (m3 > 0.f ? m3 : NEG_SLOPE * m3) * at3;

        #pragma unroll
        for (int off = 32; off; off >>= 1) {
            m0 += __shfl_xor(m0, off, 64);
            m1 += __shfl_xor(m1, off, 64);
            m2 += __shfl_xor(m2, off, 64);
            m3 += __shfl_xor(m3, off, 64);
        }
        const float e0 = __expf(m0);
        const float e1 = __expf(m1);
        const float e2 = __expf(m2);
        const float e3 = __expf(m3);

        float* pa = acc + (size_t)d * 256;
        atomicAdd(pa + lane,        e0 * l0);
        atomicAdd(pa + 64 + lane,   e1 * l1);
        atomicAdd(pa + 128 + lane,  e2 * l2);
        atomicAdd(pa + 192 + lane,  e3 * l3);
        if (lane < 4) {
            const float ev = lane == 0 ? e0 : lane == 1 ? e1 : lane == 2 ? e2 : e3;
            atomicAdd(denom + (size_t)d * 4 + lane, ev);
        }
    }
}

// ---------------------------------------------------------------------------
// Layer-2 edge pass (H=1, C=128): one wave per edge; lane l owns channels
// l and l+64.
// ---------------------------------------------------------------------------
__global__ __launch_bounds__(256)
void edge2(const float* __restrict__ xl, const float* __restrict__ xr,
           const int* __restrict__ src, const int* __restrict__ dst,
           const float* __restrict__ att,
           float* __restrict__ acc, float* __restrict__ denom, int E)
{
    const int lane = threadIdx.x & 63;
    int w = (blockIdx.x * blockDim.x + threadIdx.x) >> 6;
    const int nw = (gridDim.x * blockDim.x) >> 6;
    const float at0 = att[lane];
    const float at1 = att[64 + lane];

    for (int e = w; e < E; e += nw) {
        const int s = src[e];
        const int d = dst[e];
        const float* pl = xl + (size_t)s * 128;
        const float* pr = xr + (size_t)d * 128;
        const float l0 = pl[lane];
        const float l1 = pl[64 + lane];
        float m0 = l0 + pr[lane];      m0 = (m0 > 0.f ? m0 : NEG_SLOPE * m0) * at0;
        float m1 = l1 + pr[64 + lane]; m1 = (m1 > 0.f ? m1 : NEG_SLOPE * m1) * at1;
        float t = m0 + m1;
        #pragma unroll
        for (int off = 32; off; off >>= 1)
            t += __shfl_xor(t, off, 64);
        const float ee = __expf(t);

        float* pa = acc + (size_t)d * 128;
        atomicAdd(pa + lane,       ee * l0);
        atomicAdd(pa + 64 + lane,  ee * l1);
        if (lane == 0)
            atomicAdd(denom + d, ee);
    }
}

// h = ELU(acc/(denom+EPS) + b1), in place on acc. [N,256]
__global__ __launch_bounds__(256)
void fin1(float* __restrict__ acc, const float* __restrict__ denom,
          const float* __restrict__ b)
{
    const int i = blockIdx.x * blockDim.x + threadIdx.x;
    if (i < N_NODES * 256) {
        const int node = i >> 8;
        const int hd = (i >> 6) & 3;
        float v = acc[i] / (denom[node * 4 + hd] + EPS) + b[i & 255];
        acc[i] = v > 0.f ? v : __expf(v) - 1.f;
    }
}

// out = acc/(denom+EPS) + b2. [N,128]
__global__ __launch_bounds__(256)
void fin2(const float* __restrict__ acc, const float* __restrict__ denom,
          const float* __restrict__ b, float* __restrict__ out)
{
    const int i = blockIdx.x * blockDim.x + threadIdx.x;
    if (i < N_NODES * 128) {
        const int node = i >> 7;
        out[i] = acc[i] / (denom[node] + EPS) + b[i & 127];
    }
}

extern "C" void kernel_launch(void* const* d_in, const int* in_sizes, int n_in,
                              void* d_out, int out_size, void* d_ws, size_t ws_size,
                              hipStream_t stream)
{
    const float* x    = (const float*)d_in[0];
    const int*   ei   = (const int*)d_in[1];
    const float* Wl1  = (const float*)d_in[2];
    const float* Wr1  = (const float*)d_in[3];
    const float* att1 = (const float*)d_in[4];
    const float* b1   = (const float*)d_in[5];
    const float* Wl2  = (const float*)d_in[6];
    const float* Wr2  = (const float*)d_in[7];
    const float* att2 = (const float*)d_in[8];
    const float* b2   = (const float*)d_in[9];
    const int* src = ei;
    const int* dst = ei + E_EDGES;
    float* out = (float*)d_out;

    // Workspace layout (fp32 elements):
    //   bufA [N*256]: xl1; later xl2 [N*128] + xr2 [N*128]
    //   bufB [N*256]: xr1; later acc2 [N*128] + den2 [N]
    //   bufC [N*256]: acc1 -> h (in place)
    //   den1 [N*4]
    float* bufA = (float*)d_ws;
    float* bufB = bufA + (size_t)N_NODES * 256;
    float* bufC = bufB + (size_t)N_NODES * 256;
    float* den1 = bufC + (size_t)N_NODES * 256;
    float* xl2  = bufA;
    float* xr2  = bufA + (size_t)N_NODES * 128;
    float* acc2 = bufB;
    float* den2 = bufB + (size_t)N_NODES * 128;

    // zero acc1 + den1 (contiguous)
    hipMemsetAsync(bufC, 0, ((size_t)N_NODES * 256 + N_NODES * 4) * sizeof(float), stream);

    const dim3 blk(256);
    // Layer 1 GEMMs: [50000,128] @ [128,256]
    gemm64<<<dim3(256 / 64, (N_NODES + 63) / 64), blk, 0, stream>>>(x, Wl1, bufA, N_NODES, 128, 256);
    gemm64<<<dim3(256 / 64, (N_NODES + 63) / 64), blk, 0, stream>>>(x, Wr1, bufB, N_NODES, 128, 256);

    edge1<<<4096, blk, 0, stream>>>(bufA, bufB, src, dst, att1, bufC, den1, E_EDGES);
    fin1<<<(N_NODES * 256 + 255) / 256, blk, 0, stream>>>(bufC, den1, b1);

    // Layer 2 GEMMs: [50000,256] @ [256,128]  (reads h=bufC, writes into bufA)
    gemm64<<<dim3(128 / 64, (N_NODES + 63) / 64), blk, 0, stream>>>(bufC, Wl2, xl2, N_NODES, 256, 128);
    gemm64<<<dim3(128 / 64, (N_NODES + 63) / 64), blk, 0, stream>>>(bufC, Wr2, xr2, N_NODES, 256, 128);

    // zero acc2 + den2 (contiguous, overlays bufB which is dead now)
    hipMemsetAsync(acc2, 0, ((size_t)N_NODES * 128 + N_NODES) * sizeof(float), stream);

    edge2<<<4096, blk, 0, stream>>>(xl2, xr2, src, dst, att2, acc2, den2, E_EDGES);
    fin2<<<(N_NODES * 128 + 255) / 256, blk, 0, stream>>>(acc2, den2, b2, out);
}

// Round 2
// 836.580 us; speedup vs baseline: 1.7126x; 1.7126x over previous
//
#include <hip/hip_runtime.h>
#include <hip/hip_bf16.h>
#include <math.h>

#define N_NODES 50000
#define E_EDGES 800000
#define NEG_SLOPE 0.2f
#define EPS 1e-16f

// ---------------------------------------------------------------------------
// Tiled fp32 GEMM: Y[N,M] = X[N,K] @ W[K,M].  64x64 tile, 256 threads, 4x4
// micro-tile per thread.
// ---------------------------------------------------------------------------
__global__ __launch_bounds__(256)
void gemm64(const float* __restrict__ X, const float* __restrict__ W,
            float* __restrict__ Y, int Nrows, int K, int M)
{
    __shared__ float As[64][65];
    __shared__ float Bs[64][64];
    const int tid = threadIdx.x;
    const int tx = tid & 15;
    const int ty = tid >> 4;
    const int row0 = blockIdx.y * 64;
    const int col0 = blockIdx.x * 64;

    float acc[4][4] = {};

    for (int k0 = 0; k0 < K; k0 += 64) {
        #pragma unroll
        for (int i = 0; i < 4; ++i) {
            const int r = (tid >> 4) + i * 16;
            const int c = (tid & 15) * 4;
            const int gr = row0 + r;
            float4 v = make_float4(0.f, 0.f, 0.f, 0.f);
            if (gr < Nrows)
                v = *(const float4*)(X + (size_t)gr * K + k0 + c);
            As[r][c + 0] = v.x; As[r][c + 1] = v.y;
            As[r][c + 2] = v.z; As[r][c + 3] = v.w;
            const float4 w = *(const float4*)(W + (size_t)(k0 + r) * M + col0 + c);
            *(float4*)&Bs[r][c] = w;
        }
        __syncthreads();

        #pragma unroll
        for (int k = 0; k < 64; ++k) {
            const float4 b = *(float4*)&Bs[k][tx * 4];
            const float a0 = As[ty * 4 + 0][k];
            const float a1 = As[ty * 4 + 1][k];
            const float a2 = As[ty * 4 + 2][k];
            const float a3 = As[ty * 4 + 3][k];
            acc[0][0] += a0 * b.x; acc[0][1] += a0 * b.y; acc[0][2] += a0 * b.z; acc[0][3] += a0 * b.w;
            acc[1][0] += a1 * b.x; acc[1][1] += a1 * b.y; acc[1][2] += a1 * b.z; acc[1][3] += a1 * b.w;
            acc[2][0] += a2 * b.x; acc[2][1] += a2 * b.y; acc[2][2] += a2 * b.z; acc[2][3] += a2 * b.w;
            acc[3][0] += a3 * b.x; acc[3][1] += a3 * b.y; acc[3][2] += a3 * b.z; acc[3][3] += a3 * b.w;
        }
        __syncthreads();
    }

    #pragma unroll
    for (int i = 0; i < 4; ++i) {
        const int gr = row0 + ty * 4 + i;
        if (gr < Nrows) {
            float4 v = make_float4(acc[i][0], acc[i][1], acc[i][2], acc[i][3]);
            *(float4*)(Y + (size_t)gr * M + col0 + tx * 4) = v;
        }
    }
}

// ---------------------------------------------------------------------------
// CSR build: histogram of dst -> exclusive scan -> scatter src sorted by dst.
// ---------------------------------------------------------------------------
__global__ __launch_bounds__(256)
void hist_dst(const int* __restrict__ dst, int* __restrict__ deg, int E)
{
    int i = blockIdx.x * blockDim.x + threadIdx.x;
    if (i < E) atomicAdd(&deg[dst[i]], 1);
}

#define SCAN_T 1024
#define SCAN_CHUNK 49   // 1024*49 = 50176 >= 50000
__global__ __launch_bounds__(SCAN_T)
void scan_deg(const int* __restrict__ deg, int* __restrict__ rowptr,
              int* __restrict__ cursor)
{
    __shared__ int s[SCAN_T];
    const int t = threadIdx.x;
    const int base = t * SCAN_CHUNK;
    int sum = 0;
    for (int i = 0; i < SCAN_CHUNK; ++i) {
        int idx = base + i;
        if (idx < N_NODES) sum += deg[idx];
    }
    s[t] = sum;
    __syncthreads();
    for (int off = 1; off < SCAN_T; off <<= 1) {
        int v = (t >= off) ? s[t - off] : 0;
        __syncthreads();
        s[t] += v;
        __syncthreads();
    }
    int run = (t == 0) ? 0 : s[t - 1];
    for (int i = 0; i < SCAN_CHUNK; ++i) {
        int idx = base + i;
        if (idx < N_NODES) {
            rowptr[idx] = run;
            cursor[idx] = run;
            run += deg[idx];
        }
    }
    if (t == 0) rowptr[N_NODES] = E_EDGES;
}

__global__ __launch_bounds__(256)
void scatter_edges(const int* __restrict__ src, const int* __restrict__ dst,
                   int* __restrict__ cursor, int* __restrict__ ssrc, int E)
{
    int i = blockIdx.x * blockDim.x + threadIdx.x;
    if (i < E) {
        int pos = atomicAdd(&cursor[dst[i]], 1);
        ssrc[pos] = src[i];
    }
}

// ---------------------------------------------------------------------------
// Layer-1 aggregation, node-parallel (H=4, C=64). One wave per dst node.
// Lane l owns channel h*64+l. Registers hold running numerator + denominator;
// epilogue fuses normalize + bias + ELU. No float atomics anywhere.
// ---------------------------------------------------------------------------
__global__ __launch_bounds__(256)
void agg1(const float* __restrict__ xl, const float* __restrict__ xr,
          const int* __restrict__ rowptr, const int* __restrict__ ssrc,
          const float* __restrict__ att, const float* __restrict__ b,
          float* __restrict__ h)
{
    const int w = (blockIdx.x * blockDim.x + threadIdx.x) >> 6;
    if (w >= N_NODES) return;
    const int lane = threadIdx.x & 63;

    const float at0 = att[lane];
    const float at1 = att[64 + lane];
    const float at2 = att[128 + lane];
    const float at3 = att[192 + lane];

    const float* pr = xr + (size_t)w * 256;
    const float r0 = pr[lane];
    const float r1 = pr[64 + lane];
    const float r2 = pr[128 + lane];
    const float r3 = pr[192 + lane];

    float a0 = 0.f, a1 = 0.f, a2 = 0.f, a3 = 0.f;
    float d0 = 0.f, d1 = 0.f, d2 = 0.f, d3 = 0.f;

    const int beg = rowptr[w], end = rowptr[w + 1];
    for (int i = beg; i < end; ++i) {
        const int s = ssrc[i];
        const float* pl = xl + (size_t)s * 256;
        const float l0 = pl[lane];
        const float l1 = pl[64 + lane];
        const float l2 = pl[128 + lane];
        const float l3 = pl[192 + lane];

        float m0 = l0 + r0; m0 = (m0 > 0.f ? m0 : NEG_SLOPE * m0) * at0;
        float m1 = l1 + r1; m1 = (m1 > 0.f ? m1 : NEG_SLOPE * m1) * at1;
        float m2 = l2 + r2; m2 = (m2 > 0.f ? m2 : NEG_SLOPE * m2) * at2;
        float m3 = l3 + r3; m3 = (m3 > 0.f ? m3 : NEG_SLOPE * m3) * at3;

        #pragma unroll
        for (int off = 32; off; off >>= 1) {
            m0 += __shfl_xor(m0, off, 64);
            m1 += __shfl_xor(m1, off, 64);
            m2 += __shfl_xor(m2, off, 64);
            m3 += __shfl_xor(m3, off, 64);
        }
        const float e0 = __expf(m0);
        const float e1 = __expf(m1);
        const float e2 = __expf(m2);
        const float e3 = __expf(m3);

        a0 += e0 * l0; d0 += e0;
        a1 += e1 * l1; d1 += e1;
        a2 += e2 * l2; d2 += e2;
        a3 += e3 * l3; d3 += e3;
    }

    float* ph = h + (size_t)w * 256;
    float v0 = a0 / (d0 + EPS) + b[lane];
    float v1 = a1 / (d1 + EPS) + b[64 + lane];
    float v2 = a2 / (d2 + EPS) + b[128 + lane];
    float v3 = a3 / (d3 + EPS) + b[192 + lane];
    ph[lane]        = v0 > 0.f ? v0 : __expf(v0) - 1.f;
    ph[64 + lane]   = v1 > 0.f ? v1 : __expf(v1) - 1.f;
    ph[128 + lane]  = v2 > 0.f ? v2 : __expf(v2) - 1.f;
    ph[192 + lane]  = v3 > 0.f ? v3 : __expf(v3) - 1.f;
}

// ---------------------------------------------------------------------------
// Layer-2 aggregation, node-parallel (H=1, C=128). Lane l owns ch l, l+64.
// Fuses normalize + bias; writes final output.
// ---------------------------------------------------------------------------
__global__ __launch_bounds__(256)
void agg2(const float* __restrict__ xl, const float* __restrict__ xr,
          const int* __restrict__ rowptr, const int* __restrict__ ssrc,
          const float* __restrict__ att, const float* __restrict__ b,
          float* __restrict__ out)
{
    const int w = (blockIdx.x * blockDim.x + threadIdx.x) >> 6;
    if (w >= N_NODES) return;
    const int lane = threadIdx.x & 63;

    const float at0 = att[lane];
    const float at1 = att[64 + lane];

    const float* pr = xr + (size_t)w * 128;
    const float r0 = pr[lane];
    const float r1 = pr[64 + lane];

    float a0 = 0.f, a1 = 0.f, den = 0.f;

    const int beg = rowptr[w], end = rowptr[w + 1];
    for (int i = beg; i < end; ++i) {
        const int s = ssrc[i];
        const float* pl = xl + (size_t)s * 128;
        const float l0 = pl[lane];
        const float l1 = pl[64 + lane];

        float m0 = l0 + r0; m0 = (m0 > 0.f ? m0 : NEG_SLOPE * m0) * at0;
        float m1 = l1 + r1; m1 = (m1 > 0.f ? m1 : NEG_SLOPE * m1) * at1;
        float t = m0 + m1;
        #pragma unroll
        for (int off = 32; off; off >>= 1)
            t += __shfl_xor(t, off, 64);
        const float ee = __expf(t);
        a0 += ee * l0;
        a1 += ee * l1;
        den += ee;
    }

    float* po = out + (size_t)w * 128;
    po[lane]      = a0 / (den + EPS) + b[lane];
    po[64 + lane] = a1 / (den + EPS) + b[64 + lane];
}

extern "C" void kernel_launch(void* const* d_in, const int* in_sizes, int n_in,
                              void* d_out, int out_size, void* d_ws, size_t ws_size,
                              hipStream_t stream)
{
    const float* x    = (const float*)d_in[0];
    const int*   ei   = (const int*)d_in[1];
    const float* Wl1  = (const float*)d_in[2];
    const float* Wr1  = (const float*)d_in[3];
    const float* att1 = (const float*)d_in[4];
    const float* b1   = (const float*)d_in[5];
    const float* Wl2  = (const float*)d_in[6];
    const float* Wr2  = (const float*)d_in[7];
    const float* att2 = (const float*)d_in[8];
    const float* b2   = (const float*)d_in[9];
    const int* src = ei;
    const int* dst = ei + E_EDGES;
    float* out = (float*)d_out;

    // Workspace layout (fp32 elements):
    //   bufA [N*256]: xl1; reused after agg1 as xl2 [N*128] + xr2 [N*128]
    //   bufB [N*256]: xr1
    //   bufC [N*256]: h (ELU output of layer 1)
    //   ints: rowptr[N+1], cursor[N], deg[N], ssrc[E]
    float* bufA = (float*)d_ws;
    float* bufB = bufA + (size_t)N_NODES * 256;
    float* bufC = bufB + (size_t)N_NODES * 256;
    int*   rowptr = (int*)(bufC + (size_t)N_NODES * 256);
    int*   cursor = rowptr + (N_NODES + 1);
    int*   deg    = cursor + N_NODES;
    int*   ssrc   = deg + N_NODES;
    float* xl2 = bufA;
    float* xr2 = bufA + (size_t)N_NODES * 128;

    const dim3 blk(256);

    // --- CSR build (int atomics only, ~3.6 MB of metadata) ---
    hipMemsetAsync(deg, 0, N_NODES * sizeof(int), stream);
    hist_dst<<<(E_EDGES + 255) / 256, blk, 0, stream>>>(dst, deg, E_EDGES);
    scan_deg<<<1, SCAN_T, 0, stream>>>(deg, rowptr, cursor);
    scatter_edges<<<(E_EDGES + 255) / 256, blk, 0, stream>>>(src, dst, cursor, ssrc, E_EDGES);

    // --- Layer 1 ---
    gemm64<<<dim3(256 / 64, (N_NODES + 63) / 64), blk, 0, stream>>>(x, Wl1, bufA, N_NODES, 128, 256);
    gemm64<<<dim3(256 / 64, (N_NODES + 63) / 64), blk, 0, stream>>>(x, Wr1, bufB, N_NODES, 128, 256);
    agg1<<<(N_NODES * 64 + 255) / 256, blk, 0, stream>>>(bufA, bufB, rowptr, ssrc, att1, b1, bufC);

    // --- Layer 2 ---
    gemm64<<<dim3(128 / 64, (N_NODES + 63) / 64), blk, 0, stream>>>(bufC, Wl2, xl2, N_NODES, 256, 128);
    gemm64<<<dim3(128 / 64, (N_NODES + 63) / 64), blk, 0, stream>>>(bufC, Wr2, xr2, N_NODES, 256, 128);
    agg2<<<(N_NODES * 64 + 255) / 256, blk, 0, stream>>>(xl2, xr2, rowptr, ssrc, att2, b2, out);
}

// Round 3
// 722.964 us; speedup vs baseline: 1.9817x; 1.1572x over previous
//
#include <hip/hip_runtime.h>
#include <hip/hip_bf16.h>
#include <math.h>

#define N_NODES 50000
#define E_EDGES 800000
#define NEG_SLOPE 0.2f
#define EPS 1e-16f

__device__ __forceinline__ float leaky(float v) {
    return v > 0.f ? v : NEG_SLOPE * v;
}

// ---------------------------------------------------------------------------
// Tiled fp32 GEMM: Y[N,M] = X[N,K] @ W[K,M].  64x64 tile, 256 threads, 4x4
// micro-tile per thread.
// ---------------------------------------------------------------------------
__global__ __launch_bounds__(256)
void gemm64(const float* __restrict__ X, const float* __restrict__ W,
            float* __restrict__ Y, int Nrows, int K, int M)
{
    __shared__ float As[64][65];
    __shared__ float Bs[64][64];
    const int tid = threadIdx.x;
    const int tx = tid & 15;
    const int ty = tid >> 4;
    const int row0 = blockIdx.y * 64;
    const int col0 = blockIdx.x * 64;

    float acc[4][4] = {};

    for (int k0 = 0; k0 < K; k0 += 64) {
        #pragma unroll
        for (int i = 0; i < 4; ++i) {
            const int r = (tid >> 4) + i * 16;
            const int c = (tid & 15) * 4;
            const int gr = row0 + r;
            float4 v = make_float4(0.f, 0.f, 0.f, 0.f);
            if (gr < Nrows)
                v = *(const float4*)(X + (size_t)gr * K + k0 + c);
            As[r][c + 0] = v.x; As[r][c + 1] = v.y;
            As[r][c + 2] = v.z; As[r][c + 3] = v.w;
            const float4 w = *(const float4*)(W + (size_t)(k0 + r) * M + col0 + c);
            *(float4*)&Bs[r][c] = w;
        }
        __syncthreads();

        #pragma unroll
        for (int k = 0; k < 64; ++k) {
            const float4 b = *(float4*)&Bs[k][tx * 4];
            const float a0 = As[ty * 4 + 0][k];
            const float a1 = As[ty * 4 + 1][k];
            const float a2 = As[ty * 4 + 2][k];
            const float a3 = As[ty * 4 + 3][k];
            acc[0][0] += a0 * b.x; acc[0][1] += a0 * b.y; acc[0][2] += a0 * b.z; acc[0][3] += a0 * b.w;
            acc[1][0] += a1 * b.x; acc[1][1] += a1 * b.y; acc[1][2] += a1 * b.z; acc[1][3] += a1 * b.w;
            acc[2][0] += a2 * b.x; acc[2][1] += a2 * b.y; acc[2][2] += a2 * b.z; acc[2][3] += a2 * b.w;
            acc[3][0] += a3 * b.x; acc[3][1] += a3 * b.y; acc[3][2] += a3 * b.z; acc[3][3] += a3 * b.w;
        }
        __syncthreads();
    }

    #pragma unroll
    for (int i = 0; i < 4; ++i) {
        const int gr = row0 + ty * 4 + i;
        if (gr < Nrows) {
            float4 v = make_float4(acc[i][0], acc[i][1], acc[i][2], acc[i][3]);
            *(float4*)(Y + (size_t)gr * M + col0 + tx * 4) = v;
        }
    }
}

// ---------------------------------------------------------------------------
// CSR build: histogram of dst -> exclusive scan -> scatter src sorted by dst.
// ---------------------------------------------------------------------------
__global__ __launch_bounds__(256)
void hist_dst(const int* __restrict__ dst, int* __restrict__ deg, int E)
{
    int i = blockIdx.x * blockDim.x + threadIdx.x;
    if (i < E) atomicAdd(&deg[dst[i]], 1);
}

#define SCAN_T 1024
#define SCAN_CHUNK 49   // 1024*49 = 50176 >= 50000
__global__ __launch_bounds__(SCAN_T)
void scan_deg(const int* __restrict__ deg, int* __restrict__ rowptr,
              int* __restrict__ cursor)
{
    __shared__ int s[SCAN_T];
    const int t = threadIdx.x;
    const int base = t * SCAN_CHUNK;
    int sum = 0;
    for (int i = 0; i < SCAN_CHUNK; ++i) {
        int idx = base + i;
        if (idx < N_NODES) sum += deg[idx];
    }
    s[t] = sum;
    __syncthreads();
    for (int off = 1; off < SCAN_T; off <<= 1) {
        int v = (t >= off) ? s[t - off] : 0;
        __syncthreads();
        s[t] += v;
        __syncthreads();
    }
    int run = (t == 0) ? 0 : s[t - 1];
    for (int i = 0; i < SCAN_CHUNK; ++i) {
        int idx = base + i;
        if (idx < N_NODES) {
            rowptr[idx] = run;
            cursor[idx] = run;
            run += deg[idx];
        }
    }
    if (t == 0) rowptr[N_NODES] = E_EDGES;
}

__global__ __launch_bounds__(256)
void scatter_edges(const int* __restrict__ src, const int* __restrict__ dst,
                   int* __restrict__ cursor, int* __restrict__ ssrc, int E)
{
    int i = blockIdx.x * blockDim.x + threadIdx.x;
    if (i < E) {
        int pos = atomicAdd(&cursor[dst[i]], 1);
        ssrc[pos] = src[i];
    }
}

// ---------------------------------------------------------------------------
// Layer-1 aggregation (H=4, C=64). One wave per dst node. Lane l owns
// channels 4l..4l+3 (head = l>>4). One float4 gather per lane per edge;
// per-head score needs only a 16-lane butterfly (4 shuffles) + 1 exp.
// ---------------------------------------------------------------------------
__global__ __launch_bounds__(256)
void agg1(const float* __restrict__ xl, const float* __restrict__ xr,
          const int* __restrict__ rowptr, const int* __restrict__ ssrc,
          const float* __restrict__ att, const float* __restrict__ b,
          float* __restrict__ h)
{
    const int w = (blockIdx.x * blockDim.x + threadIdx.x) >> 6;
    if (w >= N_NODES) return;
    const int lane = threadIdx.x & 63;
    const int ch = lane * 4;                      // = head*64 + quad*4

    const float4 at = *(const float4*)(att + ch);
    const float4 bb = *(const float4*)(b + ch);
    const float4 r  = *(const float4*)(xr + (size_t)w * 256 + ch);

    float4 a = make_float4(0.f, 0.f, 0.f, 0.f);
    float den = 0.f;

    const int beg = rowptr[w], end = rowptr[w + 1];
    for (int i = beg; i < end; ++i) {
        const int s = ssrc[i];
        const float4 L = *(const float4*)(xl + (size_t)s * 256 + ch);

        float m = leaky(L.x + r.x) * at.x
                + leaky(L.y + r.y) * at.y
                + leaky(L.z + r.z) * at.z
                + leaky(L.w + r.w) * at.w;
        // reduce over the 16 lanes of this head
        m += __shfl_xor(m, 1, 64);
        m += __shfl_xor(m, 2, 64);
        m += __shfl_xor(m, 4, 64);
        m += __shfl_xor(m, 8, 64);
        const float e = __expf(m);
        a.x += e * L.x; a.y += e * L.y; a.z += e * L.z; a.w += e * L.w;
        den += e;
    }

    const float inv = 1.f / (den + EPS);
    float v0 = a.x * inv + bb.x;
    float v1 = a.y * inv + bb.y;
    float v2 = a.z * inv + bb.z;
    float v3 = a.w * inv + bb.w;
    float4 o;
    o.x = v0 > 0.f ? v0 : __expf(v0) - 1.f;
    o.y = v1 > 0.f ? v1 : __expf(v1) - 1.f;
    o.z = v2 > 0.f ? v2 : __expf(v2) - 1.f;
    o.w = v3 > 0.f ? v3 : __expf(v3) - 1.f;
    *(float4*)(h + (size_t)w * 256 + ch) = o;
}

// ---------------------------------------------------------------------------
// Layer-2 aggregation (H=1, C=128). One wave per dst node; the two 32-lane
// halves process two edges per iteration. Lane owns channels 4*(lane&31)..+3.
// 5-level 32-lane butterfly per edge-pair; cross-half combine in epilogue.
// ---------------------------------------------------------------------------
__global__ __launch_bounds__(256)
void agg2(const float* __restrict__ xl, const float* __restrict__ xr,
          const int* __restrict__ rowptr, const int* __restrict__ ssrc,
          const float* __restrict__ att, const float* __restrict__ b,
          float* __restrict__ out)
{
    const int w = (blockIdx.x * blockDim.x + threadIdx.x) >> 6;
    if (w >= N_NODES) return;
    const int lane = threadIdx.x & 63;
    const int half = lane >> 5;
    const int ch = (lane & 31) * 4;

    const float4 at = *(const float4*)(att + ch);
    const float4 bb = *(const float4*)(b + ch);
    const float4 r  = *(const float4*)(xr + (size_t)w * 128 + ch);

    float4 a = make_float4(0.f, 0.f, 0.f, 0.f);
    float den = 0.f;

    const int beg = rowptr[w], end = rowptr[w + 1];
    for (int i = beg + half; i < end; i += 2) {
        const int s = ssrc[i];
        const float4 L = *(const float4*)(xl + (size_t)s * 128 + ch);

        float m = leaky(L.x + r.x) * at.x
                + leaky(L.y + r.y) * at.y
                + leaky(L.z + r.z) * at.z
                + leaky(L.w + r.w) * at.w;
        // reduce over this 32-lane half
        m += __shfl_xor(m, 1, 64);
        m += __shfl_xor(m, 2, 64);
        m += __shfl_xor(m, 4, 64);
        m += __shfl_xor(m, 8, 64);
        m += __shfl_xor(m, 16, 64);
        const float e = __expf(m);
        a.x += e * L.x; a.y += e * L.y; a.z += e * L.z; a.w += e * L.w;
        den += e;
    }

    // combine the two halves (lane and lane^32 hold the same channels)
    a.x += __shfl_xor(a.x, 32, 64);
    a.y += __shfl_xor(a.y, 32, 64);
    a.z += __shfl_xor(a.z, 32, 64);
    a.w += __shfl_xor(a.w, 32, 64);
    den += __shfl_xor(den, 32, 64);

    if (half == 0) {
        const float inv = 1.f / (den + EPS);
        float4 o;
        o.x = a.x * inv + bb.x;
        o.y = a.y * inv + bb.y;
        o.z = a.z * inv + bb.z;
        o.w = a.w * inv + bb.w;
        *(float4*)(out + (size_t)w * 128 + ch) = o;
    }
}

extern "C" void kernel_launch(void* const* d_in, const int* in_sizes, int n_in,
                              void* d_out, int out_size, void* d_ws, size_t ws_size,
                              hipStream_t stream)
{
    const float* x    = (const float*)d_in[0];
    const int*   ei   = (const int*)d_in[1];
    const float* Wl1  = (const float*)d_in[2];
    const float* Wr1  = (const float*)d_in[3];
    const float* att1 = (const float*)d_in[4];
    const float* b1   = (const float*)d_in[5];
    const float* Wl2  = (const float*)d_in[6];
    const float* Wr2  = (const float*)d_in[7];
    const float* att2 = (const float*)d_in[8];
    const float* b2   = (const float*)d_in[9];
    const int* src = ei;
    const int* dst = ei + E_EDGES;
    float* out = (float*)d_out;

    // Workspace layout (fp32 elements):
    //   bufA [N*256]: xl1; reused after agg1 as xl2 [N*128] + xr2 [N*128]
    //   bufB [N*256]: xr1
    //   bufC [N*256]: h (ELU output of layer 1)
    //   ints: rowptr[N+1], cursor[N], deg[N], ssrc[E]
    float* bufA = (float*)d_ws;
    float* bufB = bufA + (size_t)N_NODES * 256;
    float* bufC = bufB + (size_t)N_NODES * 256;
    int*   rowptr = (int*)(bufC + (size_t)N_NODES * 256);
    int*   cursor = rowptr + (N_NODES + 1);
    int*   deg    = cursor + N_NODES;
    int*   ssrc   = deg + N_NODES;
    float* xl2 = bufA;
    float* xr2 = bufA + (size_t)N_NODES * 128;

    const dim3 blk(256);

    // --- CSR build (int atomics only) ---
    hipMemsetAsync(deg, 0, N_NODES * sizeof(int), stream);
    hist_dst<<<(E_EDGES + 255) / 256, blk, 0, stream>>>(dst, deg, E_EDGES);
    scan_deg<<<1, SCAN_T, 0, stream>>>(deg, rowptr, cursor);
    scatter_edges<<<(E_EDGES + 255) / 256, blk, 0, stream>>>(src, dst, cursor, ssrc, E_EDGES);

    // --- Layer 1 ---
    gemm64<<<dim3(256 / 64, (N_NODES + 63) / 64), blk, 0, stream>>>(x, Wl1, bufA, N_NODES, 128, 256);
    gemm64<<<dim3(256 / 64, (N_NODES + 63) / 64), blk, 0, stream>>>(x, Wr1, bufB, N_NODES, 128, 256);
    agg1<<<(N_NODES * 64 + 255) / 256, blk, 0, stream>>>(bufA, bufB, rowptr, ssrc, att1, b1, bufC);

    // --- Layer 2 ---
    gemm64<<<dim3(128 / 64, (N_NODES + 63) / 64), blk, 0, stream>>>(bufC, Wl2, xl2, N_NODES, 256, 128);
    gemm64<<<dim3(128 / 64, (N_NODES + 63) / 64), blk, 0, stream>>>(bufC, Wr2, xr2, N_NODES, 256, 128);
    agg2<<<(N_NODES * 64 + 255) / 256, blk, 0, stream>>>(xl2, xr2, rowptr, ssrc, att2, b2, out);
}

// Round 4
// 688.609 us; speedup vs baseline: 2.0806x; 1.0499x over previous
//
#include <hip/hip_runtime.h>
#include <hip/hip_bf16.h>
#include <hip/hip_fp16.h>
#include <math.h>

#define N_NODES 50000
#define E_EDGES 800000
#define NEG_SLOPE 0.2f
#define EPS 1e-16f

__device__ __forceinline__ float leaky(float v) {
    return v > 0.f ? v : NEG_SLOPE * v;
}

// ---------------------------------------------------------------------------
// fp32 GEMM: Y[N,M] = X[N,K] @ W[K,M]. 128x128 tile, BK=32, 256 threads,
// 8x8 micro-tile. A staged TRANSPOSED (As[k][m], pad 132 -> rows 16B-aligned)
// so the inner loop is 4x ds_read_b128 + 64 fma per k. Output templated:
// float or __half.
// ---------------------------------------------------------------------------
template <typename OT>
__global__ __launch_bounds__(256)
void gemm128(const float* __restrict__ X, const float* __restrict__ W,
             OT* __restrict__ Y, int Nrows, int K, int M)
{
    __shared__ float As[32][132];   // [k][m]
    __shared__ float Bs[32][128];   // [k][n]
    const int tid = threadIdx.x;
    const int tx = tid & 15;        // 0..15 col group
    const int ty = tid >> 4;        // 0..15 row group
    const int row0 = blockIdx.y * 128;
    const int col0 = blockIdx.x * 128;

    float acc[8][8] = {};

    for (int k0 = 0; k0 < K; k0 += 32) {
        // stage X[128][32] -> As[k][m] (transposed)
        #pragma unroll
        for (int p = 0; p < 4; ++p) {
            const int r = (tid >> 3) + p * 32;
            const int c = (tid & 7) * 4;
            const int gr = row0 + r;
            float4 v = make_float4(0.f, 0.f, 0.f, 0.f);
            if (gr < Nrows)
                v = *(const float4*)(X + (size_t)gr * K + k0 + c);
            As[c + 0][r] = v.x; As[c + 1][r] = v.y;
            As[c + 2][r] = v.z; As[c + 3][r] = v.w;
        }
        // stage W[32][128] -> Bs
        #pragma unroll
        for (int p = 0; p < 4; ++p) {
            const int r = (tid >> 5) + p * 8;
            const int c = (tid & 31) * 4;
            *(float4*)&Bs[r][c] = *(const float4*)(W + (size_t)(k0 + r) * M + col0 + c);
        }
        __syncthreads();

        #pragma unroll
        for (int k = 0; k < 32; ++k) {
            float a[8], bb[8];
            *(float4*)&a[0]  = *(const float4*)&As[k][ty * 8];
            *(float4*)&a[4]  = *(const float4*)&As[k][ty * 8 + 4];
            *(float4*)&bb[0] = *(const float4*)&Bs[k][tx * 8];
            *(float4*)&bb[4] = *(const float4*)&Bs[k][tx * 8 + 4];
            #pragma unroll
            for (int i = 0; i < 8; ++i)
                #pragma unroll
                for (int j = 0; j < 8; ++j)
                    acc[i][j] += a[i] * bb[j];
        }
        __syncthreads();
    }

    #pragma unroll
    for (int i = 0; i < 8; ++i) {
        const int gr = row0 + ty * 8 + i;
        if (gr < Nrows) {
            if constexpr (sizeof(OT) == 2) {
                __half tmp[8];
                #pragma unroll
                for (int j = 0; j < 8; ++j) tmp[j] = __float2half(acc[i][j]);
                *(uint4*)((__half*)Y + (size_t)gr * M + col0 + tx * 8) = *(uint4*)tmp;
            } else {
                *(float4*)((float*)Y + (size_t)gr * M + col0 + tx * 8) =
                    make_float4(acc[i][0], acc[i][1], acc[i][2], acc[i][3]);
                *(float4*)((float*)Y + (size_t)gr * M + col0 + tx * 8 + 4) =
                    make_float4(acc[i][4], acc[i][5], acc[i][6], acc[i][7]);
            }
        }
    }
}

// ---------------------------------------------------------------------------
// CSR build: histogram of dst -> exclusive scan -> scatter src sorted by dst.
// ---------------------------------------------------------------------------
__global__ __launch_bounds__(256)
void hist_dst(const int* __restrict__ dst, int* __restrict__ deg, int E)
{
    int i = blockIdx.x * blockDim.x + threadIdx.x;
    if (i < E) atomicAdd(&deg[dst[i]], 1);
}

#define SCAN_T 1024
#define SCAN_CHUNK 49   // 1024*49 = 50176 >= 50000
__global__ __launch_bounds__(SCAN_T)
void scan_deg(const int* __restrict__ deg, int* __restrict__ rowptr,
              int* __restrict__ cursor)
{
    __shared__ int s[SCAN_T];
    const int t = threadIdx.x;
    const int base = t * SCAN_CHUNK;
    int sum = 0;
    for (int i = 0; i < SCAN_CHUNK; ++i) {
        int idx = base + i;
        if (idx < N_NODES) sum += deg[idx];
    }
    s[t] = sum;
    __syncthreads();
    for (int off = 1; off < SCAN_T; off <<= 1) {
        int v = (t >= off) ? s[t - off] : 0;
        __syncthreads();
        s[t] += v;
        __syncthreads();
    }
    int run = (t == 0) ? 0 : s[t - 1];
    for (int i = 0; i < SCAN_CHUNK; ++i) {
        int idx = base + i;
        if (idx < N_NODES) {
            rowptr[idx] = run;
            cursor[idx] = run;
            run += deg[idx];
        }
    }
    if (t == 0) rowptr[N_NODES] = E_EDGES;
}

__global__ __launch_bounds__(256)
void scatter_edges(const int* __restrict__ src, const int* __restrict__ dst,
                   int* __restrict__ cursor, int* __restrict__ ssrc, int E)
{
    int i = blockIdx.x * blockDim.x + threadIdx.x;
    if (i < E) {
        int pos = atomicAdd(&cursor[dst[i]], 1);
        ssrc[pos] = src[i];
    }
}

// ---------------------------------------------------------------------------
// Layer-1 aggregation (H=4, C=64). One wave per dst node. Lane l owns
// channels 4l..4l+3 (head = l>>4). xl gathered as fp16 (8B/lane/edge);
// 16-lane butterfly (4 shuffles) + 1 exp per edge.
// ---------------------------------------------------------------------------
__global__ __launch_bounds__(256)
void agg1(const __half* __restrict__ xl, const float* __restrict__ xr,
          const int* __restrict__ rowptr, const int* __restrict__ ssrc,
          const float* __restrict__ att, const float* __restrict__ b,
          float* __restrict__ h)
{
    const int w = (blockIdx.x * blockDim.x + threadIdx.x) >> 6;
    if (w >= N_NODES) return;
    const int lane = threadIdx.x & 63;
    const int ch = lane * 4;

    const float4 at = *(const float4*)(att + ch);
    const float4 bb = *(const float4*)(b + ch);
    const float4 r  = *(const float4*)(xr + (size_t)w * 256 + ch);

    float4 a = make_float4(0.f, 0.f, 0.f, 0.f);
    float den = 0.f;

    const int beg = rowptr[w], end = rowptr[w + 1];
    for (int i = beg; i < end; ++i) {
        const int s = ssrc[i];
        union { uint2 u; __half2 h2[2]; } U;
        U.u = *(const uint2*)(xl + (size_t)s * 256 + ch);
        const float2 p01 = __half22float2(U.h2[0]);
        const float2 p23 = __half22float2(U.h2[1]);

        float m = leaky(p01.x + r.x) * at.x
                + leaky(p01.y + r.y) * at.y
                + leaky(p23.x + r.z) * at.z
                + leaky(p23.y + r.w) * at.w;
        m += __shfl_xor(m, 1, 64);
        m += __shfl_xor(m, 2, 64);
        m += __shfl_xor(m, 4, 64);
        m += __shfl_xor(m, 8, 64);
        const float e = __expf(m);
        a.x += e * p01.x; a.y += e * p01.y;
        a.z += e * p23.x; a.w += e * p23.y;
        den += e;
    }

    const float inv = 1.f / (den + EPS);
    float v0 = a.x * inv + bb.x;
    float v1 = a.y * inv + bb.y;
    float v2 = a.z * inv + bb.z;
    float v3 = a.w * inv + bb.w;
    float4 o;
    o.x = v0 > 0.f ? v0 : __expf(v0) - 1.f;
    o.y = v1 > 0.f ? v1 : __expf(v1) - 1.f;
    o.z = v2 > 0.f ? v2 : __expf(v2) - 1.f;
    o.w = v3 > 0.f ? v3 : __expf(v3) - 1.f;
    *(float4*)(h + (size_t)w * 256 + ch) = o;
}

// ---------------------------------------------------------------------------
// Layer-2 aggregation (H=1, C=128). Two 32-lane halves process two edges per
// iteration; xl gathered as fp16 (8B/lane/edge). Cross-half combine at end.
// ---------------------------------------------------------------------------
__global__ __launch_bounds__(256)
void agg2(const __half* __restrict__ xl, const float* __restrict__ xr,
          const int* __restrict__ rowptr, const int* __restrict__ ssrc,
          const float* __restrict__ att, const float* __restrict__ b,
          float* __restrict__ out)
{
    const int w = (blockIdx.x * blockDim.x + threadIdx.x) >> 6;
    if (w >= N_NODES) return;
    const int lane = threadIdx.x & 63;
    const int half = lane >> 5;
    const int ch = (lane & 31) * 4;

    const float4 at = *(const float4*)(att + ch);
    const float4 bb = *(const float4*)(b + ch);
    const float4 r  = *(const float4*)(xr + (size_t)w * 128 + ch);

    float4 a = make_float4(0.f, 0.f, 0.f, 0.f);
    float den = 0.f;

    const int beg = rowptr[w], end = rowptr[w + 1];
    for (int i = beg + half; i < end; i += 2) {
        const int s = ssrc[i];
        union { uint2 u; __half2 h2[2]; } U;
        U.u = *(const uint2*)(xl + (size_t)s * 128 + ch);
        const float2 p01 = __half22float2(U.h2[0]);
        const float2 p23 = __half22float2(U.h2[1]);

        float m = leaky(p01.x + r.x) * at.x
                + leaky(p01.y + r.y) * at.y
                + leaky(p23.x + r.z) * at.z
                + leaky(p23.y + r.w) * at.w;
        m += __shfl_xor(m, 1, 64);
        m += __shfl_xor(m, 2, 64);
        m += __shfl_xor(m, 4, 64);
        m += __shfl_xor(m, 8, 64);
        m += __shfl_xor(m, 16, 64);
        const float e = __expf(m);
        a.x += e * p01.x; a.y += e * p01.y;
        a.z += e * p23.x; a.w += e * p23.y;
        den += e;
    }

    a.x += __shfl_xor(a.x, 32, 64);
    a.y += __shfl_xor(a.y, 32, 64);
    a.z += __shfl_xor(a.z, 32, 64);
    a.w += __shfl_xor(a.w, 32, 64);
    den += __shfl_xor(den, 32, 64);

    if (half == 0) {
        const float inv = 1.f / (den + EPS);
        float4 o;
        o.x = a.x * inv + bb.x;
        o.y = a.y * inv + bb.y;
        o.z = a.z * inv + bb.z;
        o.w = a.w * inv + bb.w;
        *(float4*)(out + (size_t)w * 128 + ch) = o;
    }
}

extern "C" void kernel_launch(void* const* d_in, const int* in_sizes, int n_in,
                              void* d_out, int out_size, void* d_ws, size_t ws_size,
                              hipStream_t stream)
{
    const float* x    = (const float*)d_in[0];
    const int*   ei   = (const int*)d_in[1];
    const float* Wl1  = (const float*)d_in[2];
    const float* Wr1  = (const float*)d_in[3];
    const float* att1 = (const float*)d_in[4];
    const float* b1   = (const float*)d_in[5];
    const float* Wl2  = (const float*)d_in[6];
    const float* Wr2  = (const float*)d_in[7];
    const float* att2 = (const float*)d_in[8];
    const float* b2   = (const float*)d_in[9];
    const int* src = ei;
    const int* dst = ei + E_EDGES;
    float* out = (float*)d_out;

    // Workspace layout:
    //   bufA: xl1 as half [N*256]  (25.6 MB); reused after agg1 as xl2h [N*128]
    //   bufB: xr1 fp32 [N*256];    reused after agg1 as xr2 fp32 [N*128]
    //   bufC: h fp32 [N*256]
    //   ints: rowptr[N+1], cursor[N], deg[N], ssrc[E]
    __half* xl1h = (__half*)d_ws;
    float*  bufB = (float*)((char*)d_ws + (size_t)N_NODES * 256 * sizeof(__half));
    float*  bufC = bufB + (size_t)N_NODES * 256;
    int* rowptr = (int*)(bufC + (size_t)N_NODES * 256);
    int* cursor = rowptr + (N_NODES + 1);
    int* deg    = cursor + N_NODES;
    int* ssrc   = deg + N_NODES;
    __half* xl2h = xl1h;                       // overlays dead xl1
    float*  xr2  = bufB;                       // overlays dead xr1

    const dim3 blk(256);

    // --- CSR build (int atomics only) ---
    hipMemsetAsync(deg, 0, N_NODES * sizeof(int), stream);
    hist_dst<<<(E_EDGES + 255) / 256, blk, 0, stream>>>(dst, deg, E_EDGES);
    scan_deg<<<1, SCAN_T, 0, stream>>>(deg, rowptr, cursor);
    scatter_edges<<<(E_EDGES + 255) / 256, blk, 0, stream>>>(src, dst, cursor, ssrc, E_EDGES);

    // --- Layer 1: [50000,128] @ [128,256] ---
    gemm128<__half><<<dim3(256 / 128, (N_NODES + 127) / 128), blk, 0, stream>>>(x, Wl1, xl1h, N_NODES, 128, 256);
    gemm128<float ><<<dim3(256 / 128, (N_NODES + 127) / 128), blk, 0, stream>>>(x, Wr1, bufB, N_NODES, 128, 256);
    agg1<<<(N_NODES * 64 + 255) / 256, blk, 0, stream>>>(xl1h, bufB, rowptr, ssrc, att1, b1, bufC);

    // --- Layer 2: [50000,256] @ [256,128] ---
    gemm128<__half><<<dim3(128 / 128, (N_NODES + 127) / 128), blk, 0, stream>>>(bufC, Wl2, xl2h, N_NODES, 256, 128);
    gemm128<float ><<<dim3(128 / 128, (N_NODES + 127) / 128), blk, 0, stream>>>(bufC, Wr2, xr2, N_NODES, 256, 128);
    agg2<<<(N_NODES * 64 + 255) / 256, blk, 0, stream>>>(xl2h, xr2, rowptr, ssrc, att2, b2, out);
}

// Round 5
// 563.655 us; speedup vs baseline: 2.5418x; 1.2217x over previous
//
#include <hip/hip_runtime.h>
#include <hip/hip_bf16.h>
#include <hip/hip_fp16.h>
#include <math.h>

#define N_NODES 50000
#define E_EDGES 800000
#define NEG_SLOPE 0.2f
#define EPS 1e-16f
#define NB_SCAN ((N_NODES + 255) / 256)   // 196

__device__ __forceinline__ float leaky(float v) {
    return v > 0.f ? v : NEG_SLOPE * v;
}

// ---------------------------------------------------------------------------
// fp32 GEMM: Y[N,M] = X[N,K] @ W[K,M]. 128x128 tile, BK=32, 256 threads,
// 8x8 micro-tile. A staged TRANSPOSED (As[k][m]) so the inner loop is pure
// ds_read_b128 + fma. Output templated: float or __half.
// ---------------------------------------------------------------------------
template <typename OT>
__global__ __launch_bounds__(256)
void gemm128(const float* __restrict__ X, const float* __restrict__ W,
             OT* __restrict__ Y, int Nrows, int K, int M)
{
    __shared__ float As[32][132];   // [k][m]
    __shared__ float Bs[32][128];   // [k][n]
    const int tid = threadIdx.x;
    const int tx = tid & 15;        // 0..15 col group
    const int ty = tid >> 4;        // 0..15 row group
    const int row0 = blockIdx.y * 128;
    const int col0 = blockIdx.x * 128;

    float acc[8][8] = {};

    for (int k0 = 0; k0 < K; k0 += 32) {
        #pragma unroll
        for (int p = 0; p < 4; ++p) {
            const int r = (tid >> 3) + p * 32;
            const int c = (tid & 7) * 4;
            const int gr = row0 + r;
            float4 v = make_float4(0.f, 0.f, 0.f, 0.f);
            if (gr < Nrows)
                v = *(const float4*)(X + (size_t)gr * K + k0 + c);
            As[c + 0][r] = v.x; As[c + 1][r] = v.y;
            As[c + 2][r] = v.z; As[c + 3][r] = v.w;
        }
        #pragma unroll
        for (int p = 0; p < 4; ++p) {
            const int r = (tid >> 5) + p * 8;
            const int c = (tid & 31) * 4;
            *(float4*)&Bs[r][c] = *(const float4*)(W + (size_t)(k0 + r) * M + col0 + c);
        }
        __syncthreads();

        #pragma unroll
        for (int k = 0; k < 32; ++k) {
            float a[8], bb[8];
            *(float4*)&a[0]  = *(const float4*)&As[k][ty * 8];
            *(float4*)&a[4]  = *(const float4*)&As[k][ty * 8 + 4];
            *(float4*)&bb[0] = *(const float4*)&Bs[k][tx * 8];
            *(float4*)&bb[4] = *(const float4*)&Bs[k][tx * 8 + 4];
            #pragma unroll
            for (int i = 0; i < 8; ++i)
                #pragma unroll
                for (int j = 0; j < 8; ++j)
                    acc[i][j] += a[i] * bb[j];
        }
        __syncthreads();
    }

    #pragma unroll
    for (int i = 0; i < 8; ++i) {
        const int gr = row0 + ty * 8 + i;
        if (gr < Nrows) {
            if constexpr (sizeof(OT) == 2) {
                __half tmp[8];
                #pragma unroll
                for (int j = 0; j < 8; ++j) tmp[j] = __float2half(acc[i][j]);
                *(uint4*)((__half*)Y + (size_t)gr * M + col0 + tx * 8) = *(uint4*)tmp;
            } else {
                *(float4*)((float*)Y + (size_t)gr * M + col0 + tx * 8) =
                    make_float4(acc[i][0], acc[i][1], acc[i][2], acc[i][3]);
                *(float4*)((float*)Y + (size_t)gr * M + col0 + tx * 8 + 4) =
                    make_float4(acc[i][4], acc[i][5], acc[i][6], acc[i][7]);
            }
        }
    }
}

// ---------------------------------------------------------------------------
// CSR build: histogram -> two-phase parallel scan -> scatter.
// ---------------------------------------------------------------------------
__global__ __launch_bounds__(256)
void hist_dst(const int* __restrict__ dst, int* __restrict__ deg, int E)
{
    int i = blockIdx.x * blockDim.x + threadIdx.x;
    if (i < E) atomicAdd(&deg[dst[i]], 1);
}

// Phase 1: block-local exclusive prefix + per-block total.
__global__ __launch_bounds__(256)
void scan_local(const int* __restrict__ deg, int* __restrict__ locpre,
                int* __restrict__ blockSum)
{
    const int i = blockIdx.x * 256 + threadIdx.x;
    const int lane = threadIdx.x & 63;
    const int wid = threadIdx.x >> 6;
    const int val = (i < N_NODES) ? deg[i] : 0;

    int v = val;
    #pragma unroll
    for (int off = 1; off < 64; off <<= 1) {
        int t = __shfl_up(v, off, 64);
        if (lane >= off) v += t;
    }
    __shared__ int ws[4];
    if (lane == 63) ws[wid] = v;
    __syncthreads();
    int woff = 0;
    for (int k = 0; k < wid; ++k) woff += ws[k];
    if (i < N_NODES) locpre[i] = woff + v - val;   // exclusive within block
    if (threadIdx.x == 255) blockSum[blockIdx.x] = woff + v;
}

// Phase 2: block b's offset = sum(blockSum[0..b-1]) via block reduce,
// then emit rowptr/cursor.
__global__ __launch_bounds__(256)
void scan_final(const int* __restrict__ locpre, const int* __restrict__ blockSum,
                int* __restrict__ rowptr, int* __restrict__ cursor)
{
    const int b = blockIdx.x;
    const int t = threadIdx.x;
    int v = (t < b) ? blockSum[t] : 0;          // NB_SCAN(=196) < 256
    #pragma unroll
    for (int off = 32; off; off >>= 1) v += __shfl_xor(v, off, 64);
    __shared__ int ws[4];
    if ((t & 63) == 0) ws[t >> 6] = v;
    __syncthreads();
    const int offset = ws[0] + ws[1] + ws[2] + ws[3];

    const int i = b * 256 + t;
    if (i < N_NODES) {
        const int rp = locpre[i] + offset;
        rowptr[i] = rp;
        cursor[i] = rp;
    }
    if (b == 0 && t == 0) rowptr[N_NODES] = E_EDGES;
}

__global__ __launch_bounds__(256)
void scatter_edges(const int* __restrict__ src, const int* __restrict__ dst,
                   int* __restrict__ cursor, int* __restrict__ ssrc, int E)
{
    int i = blockIdx.x * blockDim.x + threadIdx.x;
    if (i < E) {
        int pos = atomicAdd(&cursor[dst[i]], 1);
        ssrc[pos] = src[i];
    }
}

// ---------------------------------------------------------------------------
// Layer-1 aggregation (H=4, C=64). One wave per dst node. Lane l owns
// channels 4l..4l+3 (head = l>>4). xl gathered as fp16 (8B/lane/edge);
// 16-lane butterfly (4 shuffles) + 1 exp per edge.
// ---------------------------------------------------------------------------
__global__ __launch_bounds__(256)
void agg1(const __half* __restrict__ xl, const float* __restrict__ xr,
          const int* __restrict__ rowptr, const int* __restrict__ ssrc,
          const float* __restrict__ att, const float* __restrict__ b,
          float* __restrict__ h)
{
    const int w = (blockIdx.x * blockDim.x + threadIdx.x) >> 6;
    if (w >= N_NODES) return;
    const int lane = threadIdx.x & 63;
    const int ch = lane * 4;

    const float4 at = *(const float4*)(att + ch);
    const float4 bb = *(const float4*)(b + ch);
    const float4 r  = *(const float4*)(xr + (size_t)w * 256 + ch);

    float4 a = make_float4(0.f, 0.f, 0.f, 0.f);
    float den = 0.f;

    const int beg = rowptr[w], end = rowptr[w + 1];
    for (int i = beg; i < end; ++i) {
        const int s = ssrc[i];
        union { uint2 u; __half2 h2[2]; } U;
        U.u = *(const uint2*)(xl + (size_t)s * 256 + ch);
        const float2 p01 = __half22float2(U.h2[0]);
        const float2 p23 = __half22float2(U.h2[1]);

        float m = leaky(p01.x + r.x) * at.x
                + leaky(p01.y + r.y) * at.y
                + leaky(p23.x + r.z) * at.z
                + leaky(p23.y + r.w) * at.w;
        m += __shfl_xor(m, 1, 64);
        m += __shfl_xor(m, 2, 64);
        m += __shfl_xor(m, 4, 64);
        m += __shfl_xor(m, 8, 64);
        const float e = __expf(m);
        a.x += e * p01.x; a.y += e * p01.y;
        a.z += e * p23.x; a.w += e * p23.y;
        den += e;
    }

    const float inv = 1.f / (den + EPS);
    float v0 = a.x * inv + bb.x;
    float v1 = a.y * inv + bb.y;
    float v2 = a.z * inv + bb.z;
    float v3 = a.w * inv + bb.w;
    float4 o;
    o.x = v0 > 0.f ? v0 : __expf(v0) - 1.f;
    o.y = v1 > 0.f ? v1 : __expf(v1) - 1.f;
    o.z = v2 > 0.f ? v2 : __expf(v2) - 1.f;
    o.w = v3 > 0.f ? v3 : __expf(v3) - 1.f;
    *(float4*)(h + (size_t)w * 256 + ch) = o;
}

// ---------------------------------------------------------------------------
// Layer-2 aggregation (H=1, C=128). Two 32-lane halves process two edges per
// iteration; xl gathered as fp16 (8B/lane/edge). Cross-half combine at end.
// ---------------------------------------------------------------------------
__global__ __launch_bounds__(256)
void agg2(const __half* __restrict__ xl, const float* __restrict__ xr,
          const int* __restrict__ rowptr, const int* __restrict__ ssrc,
          const float* __restrict__ att, const float* __restrict__ b,
          float* __restrict__ out)
{
    const int w = (blockIdx.x * blockDim.x + threadIdx.x) >> 6;
    if (w >= N_NODES) return;
    const int lane = threadIdx.x & 63;
    const int half = lane >> 5;
    const int ch = (lane & 31) * 4;

    const float4 at = *(const float4*)(att + ch);
    const float4 bb = *(const float4*)(b + ch);
    const float4 r  = *(const float4*)(xr + (size_t)w * 128 + ch);

    float4 a = make_float4(0.f, 0.f, 0.f, 0.f);
    float den = 0.f;

    const int beg = rowptr[w], end = rowptr[w + 1];
    for (int i = beg + half; i < end; i += 2) {
        const int s = ssrc[i];
        union { uint2 u; __half2 h2[2]; } U;
        U.u = *(const uint2*)(xl + (size_t)s * 128 + ch);
        const float2 p01 = __half22float2(U.h2[0]);
        const float2 p23 = __half22float2(U.h2[1]);

        float m = leaky(p01.x + r.x) * at.x
                + leaky(p01.y + r.y) * at.y
                + leaky(p23.x + r.z) * at.z
                + leaky(p23.y + r.w) * at.w;
        m += __shfl_xor(m, 1, 64);
        m += __shfl_xor(m, 2, 64);
        m += __shfl_xor(m, 4, 64);
        m += __shfl_xor(m, 8, 64);
        m += __shfl_xor(m, 16, 64);
        const float e = __expf(m);
        a.x += e * p01.x; a.y += e * p01.y;
        a.z += e * p23.x; a.w += e * p23.y;
        den += e;
    }

    a.x += __shfl_xor(a.x, 32, 64);
    a.y += __shfl_xor(a.y, 32, 64);
    a.z += __shfl_xor(a.z, 32, 64);
    a.w += __shfl_xor(a.w, 32, 64);
    den += __shfl_xor(den, 32, 64);

    if (half == 0) {
        const float inv = 1.f / (den + EPS);
        float4 o;
        o.x = a.x * inv + bb.x;
        o.y = a.y * inv + bb.y;
        o.z = a.z * inv + bb.z;
        o.w = a.w * inv + bb.w;
        *(float4*)(out + (size_t)w * 128 + ch) = o;
    }
}

extern "C" void kernel_launch(void* const* d_in, const int* in_sizes, int n_in,
                              void* d_out, int out_size, void* d_ws, size_t ws_size,
                              hipStream_t stream)
{
    const float* x    = (const float*)d_in[0];
    const int*   ei   = (const int*)d_in[1];
    const float* Wl1  = (const float*)d_in[2];
    const float* Wr1  = (const float*)d_in[3];
    const float* att1 = (const float*)d_in[4];
    const float* b1   = (const float*)d_in[5];
    const float* Wl2  = (const float*)d_in[6];
    const float* Wr2  = (const float*)d_in[7];
    const float* att2 = (const float*)d_in[8];
    const float* b2   = (const float*)d_in[9];
    const int* src = ei;
    const int* dst = ei + E_EDGES;
    float* out = (float*)d_out;

    // Workspace layout:
    //   xl1h: half [N*256] (25.6 MB); reused after agg1 as xl2h [N*128]
    //   bufB: fp32 [N*256] xr1; reused as xr2 [N*128]
    //   bufC: fp32 [N*256] h
    //   ints: rowptr[N+1], cursor[N], deg[N], ssrc[E], locpre[N], blockSum[NB]
    __half* xl1h = (__half*)d_ws;
    float*  bufB = (float*)((char*)d_ws + (size_t)N_NODES * 256 * sizeof(__half));
    float*  bufC = bufB + (size_t)N_NODES * 256;
    int* rowptr   = (int*)(bufC + (size_t)N_NODES * 256);
    int* cursor   = rowptr + (N_NODES + 1);
    int* deg      = cursor + N_NODES;
    int* ssrc     = deg + N_NODES;
    int* locpre   = ssrc + E_EDGES;
    int* blockSum = locpre + N_NODES;
    __half* xl2h = xl1h;
    float*  xr2  = bufB;

    const dim3 blk(256);

    // --- CSR build ---
    hipMemsetAsync(deg, 0, N_NODES * sizeof(int), stream);
    hist_dst<<<(E_EDGES + 255) / 256, blk, 0, stream>>>(dst, deg, E_EDGES);
    scan_local<<<NB_SCAN, blk, 0, stream>>>(deg, locpre, blockSum);
    scan_final<<<NB_SCAN, blk, 0, stream>>>(locpre, blockSum, rowptr, cursor);
    scatter_edges<<<(E_EDGES + 255) / 256, blk, 0, stream>>>(src, dst, cursor, ssrc, E_EDGES);

    // --- Layer 1: [50000,128] @ [128,256] ---
    gemm128<__half><<<dim3(256 / 128, (N_NODES + 127) / 128), blk, 0, stream>>>(x, Wl1, xl1h, N_NODES, 128, 256);
    gemm128<float ><<<dim3(256 / 128, (N_NODES + 127) / 128), blk, 0, stream>>>(x, Wr1, bufB, N_NODES, 128, 256);
    agg1<<<(N_NODES * 64 + 255) / 256, blk, 0, stream>>>(xl1h, bufB, rowptr, ssrc, att1, b1, bufC);

    // --- Layer 2: [50000,256] @ [256,128] ---
    gemm128<__half><<<dim3(128 / 128, (N_NODES + 127) / 128), blk, 0, stream>>>(bufC, Wl2, xl2h, N_NODES, 256, 128);
    gemm128<float ><<<dim3(128 / 128, (N_NODES + 127) / 128), blk, 0, stream>>>(bufC, Wr2, xr2, N_NODES, 256, 128);
    agg2<<<(N_NODES * 64 + 255) / 256, blk, 0, stream>>>(xl2h, xr2, rowptr, ssrc, att2, b2, out);
}

// Round 6
// 423.826 us; speedup vs baseline: 3.3804x; 1.3299x over previous
//
#include <hip/hip_runtime.h>
#include <hip/hip_bf16.h>
#include <hip/hip_fp16.h>
#include <math.h>

#define N_NODES 50000
#define E_EDGES 800000
#define NEG_SLOPE 0.2f
#define EPS 1e-16f
#define NB_SCAN ((N_NODES + 255) / 256)   // 196

typedef _Float16 f16x8 __attribute__((ext_vector_type(8)));
typedef float    f32x4 __attribute__((ext_vector_type(4)));

__device__ __forceinline__ float leaky(float v) {
    return v > 0.f ? v : NEG_SLOPE * v;
}

// ---------------------------------------------------------------------------
// fp16->fp32-accum MFMA GEMM: Y[N,M] = X[N,K] @ Wt[M,K]^T.
// X fp16 row-major [N,K]; Wt fp16 row-major [M,K] (pre-transposed weights).
// 128x128 tile, BK=32, 256 threads = 4 waves (2x2), each wave 64x64 =
// 4x4 MFMA tiles of v_mfma_f32_16x16x32_f16.
// A-frag: lane reads As[m=lane&15][k=(lane>>4)*8 .. +7] (ds_read_b128);
// B-frag symmetric from Bs[n][k]. C/D: col=lane&15, row=(lane>>4)*4+reg.
// LDS rows padded to 40 halves (80B) -> fragment reads ~2-way (free).
// Output templated: __half or float.
// ---------------------------------------------------------------------------
template <typename OT>
__global__ __launch_bounds__(256)
void gemm_mfma(const __half* __restrict__ Xh, const __half* __restrict__ Wth,
               OT* __restrict__ Y, int Nrows, int K, int M)
{
    const _Float16* X  = (const _Float16*)Xh;
    const _Float16* Wt = (const _Float16*)Wth;
    __shared__ _Float16 As[128][40];
    __shared__ _Float16 Bs[128][40];
    const int tid  = threadIdx.x;
    const int row0 = blockIdx.x * 128;
    const int col0 = blockIdx.y * 128;
    const int lane = tid & 63;
    const int wv   = tid >> 6;
    const int wr   = (wv >> 1) * 64;     // wave row offset in tile
    const int wc   = (wv & 1) * 64;      // wave col offset in tile
    const int fm   = lane & 15;          // fragment m/n index
    const int fk   = (lane >> 4) * 8;    // fragment k offset
    const int quad = lane >> 4;

    f32x4 acc[4][4] = {};

    for (int k0 = 0; k0 < K; k0 += 32) {
        // stage A[128][32] and B[128][32]: 512 chunks of 16B each, 2/thread
        #pragma unroll
        for (int p = 0; p < 2; ++p) {
            const int idx = tid + p * 256;       // 0..511
            const int r = idx >> 2;
            const int c = (idx & 3) * 8;
            const int gr = row0 + r;
            f16x8 v = {};
            if (gr < Nrows)
                v = *(const f16x8*)(X + (size_t)gr * K + k0 + c);
            *(f16x8*)&As[r][c] = v;
            *(f16x8*)&Bs[r][c] = *(const f16x8*)(Wt + (size_t)(col0 + r) * K + k0 + c);
        }
        __syncthreads();

        f16x8 af[4], bf[4];
        #pragma unroll
        for (int i = 0; i < 4; ++i) {
            af[i] = *(const f16x8*)&As[wr + i * 16 + fm][fk];
            bf[i] = *(const f16x8*)&Bs[wc + i * 16 + fm][fk];
        }
        #pragma unroll
        for (int i = 0; i < 4; ++i)
            #pragma unroll
            for (int j = 0; j < 4; ++j)
                acc[i][j] = __builtin_amdgcn_mfma_f32_16x16x32_f16(af[i], bf[j], acc[i][j], 0, 0, 0);
        __syncthreads();
    }

    #pragma unroll
    for (int i = 0; i < 4; ++i) {
        #pragma unroll
        for (int j = 0; j < 4; ++j) {
            const int col = col0 + wc + j * 16 + fm;
            #pragma unroll
            for (int rg = 0; rg < 4; ++rg) {
                const int row = row0 + wr + i * 16 + quad * 4 + rg;
                if (row < Nrows) {
                    if constexpr (sizeof(OT) == 2)
                        ((__half*)Y)[(size_t)row * M + col] = __float2half(acc[i][j][rg]);
                    else
                        ((float*)Y)[(size_t)row * M + col] = acc[i][j][rg];
                }
            }
        }
    }
}

// ---------------------------------------------------------------------------
// Converts: x fp32 -> fp16; weight pairs fp32 [K,M] -> fp16 [2M,K] transposed.
// ---------------------------------------------------------------------------
__global__ __launch_bounds__(256)
void cvt_x(const float* __restrict__ x, __half* __restrict__ xh, int n4)
{
    const int i = blockIdx.x * blockDim.x + threadIdx.x;
    if (i < n4) {
        const float4 v = *(const float4*)(x + (size_t)i * 4);
        __half tmp[4] = { __float2half(v.x), __float2half(v.y),
                          __float2half(v.z), __float2half(v.w) };
        *(uint2*)(xh + (size_t)i * 4) = *(uint2*)tmp;
    }
}

__global__ __launch_bounds__(256)
void cvt_wpair(const float* __restrict__ Wa, const float* __restrict__ Wb,
               __half* __restrict__ Wt, int K, int M)
{
    const int id = blockIdx.x * 256 + threadIdx.x;
    if (id >= 2 * M * K) return;
    const int n = id / K, k = id - n * K;
    const float* W = (n < M) ? Wa : Wb;
    const int nn = (n < M) ? n : n - M;
    Wt[id] = __float2half(W[(size_t)k * M + nn]);
}

// ---------------------------------------------------------------------------
// CSR build: histogram -> two-phase parallel scan -> scatter.
// ---------------------------------------------------------------------------
__global__ __launch_bounds__(256)
void hist_dst(const int* __restrict__ dst, int* __restrict__ deg, int E)
{
    int i = blockIdx.x * blockDim.x + threadIdx.x;
    if (i < E) atomicAdd(&deg[dst[i]], 1);
}

__global__ __launch_bounds__(256)
void scan_local(const int* __restrict__ deg, int* __restrict__ locpre,
                int* __restrict__ blockSum)
{
    const int i = blockIdx.x * 256 + threadIdx.x;
    const int lane = threadIdx.x & 63;
    const int wid = threadIdx.x >> 6;
    const int val = (i < N_NODES) ? deg[i] : 0;

    int v = val;
    #pragma unroll
    for (int off = 1; off < 64; off <<= 1) {
        int t = __shfl_up(v, off, 64);
        if (lane >= off) v += t;
    }
    __shared__ int ws[4];
    if (lane == 63) ws[wid] = v;
    __syncthreads();
    int woff = 0;
    for (int k = 0; k < wid; ++k) woff += ws[k];
    if (i < N_NODES) locpre[i] = woff + v - val;
    if (threadIdx.x == 255) blockSum[blockIdx.x] = woff + v;
}

__global__ __launch_bounds__(256)
void scan_final(const int* __restrict__ locpre, const int* __restrict__ blockSum,
                int* __restrict__ rowptr, int* __restrict__ cursor)
{
    const int b = blockIdx.x;
    const int t = threadIdx.x;
    int v = (t < b) ? blockSum[t] : 0;          // NB_SCAN(=196) < 256
    #pragma unroll
    for (int off = 32; off; off >>= 1) v += __shfl_xor(v, off, 64);
    __shared__ int ws[4];
    if ((t & 63) == 0) ws[t >> 6] = v;
    __syncthreads();
    const int offset = ws[0] + ws[1] + ws[2] + ws[3];

    const int i = b * 256 + t;
    if (i < N_NODES) {
        const int rp = locpre[i] + offset;
        rowptr[i] = rp;
        cursor[i] = rp;
    }
    if (b == 0 && t == 0) rowptr[N_NODES] = E_EDGES;
}

__global__ __launch_bounds__(256)
void scatter_edges(const int* __restrict__ src, const int* __restrict__ dst,
                   int* __restrict__ cursor, int* __restrict__ ssrc, int E)
{
    int i = blockIdx.x * blockDim.x + threadIdx.x;
    if (i < E) {
        int pos = atomicAdd(&cursor[dst[i]], 1);
        ssrc[pos] = src[i];
    }
}

// ---------------------------------------------------------------------------
// Layer-1 aggregation (H=4, C=64). One wave per dst node. Lane l owns
// channels 4l..4l+3. xl fp16 gather; 4-shuffle head reduce; writes h as fp16.
// ---------------------------------------------------------------------------
__global__ __launch_bounds__(256)
void agg1(const __half* __restrict__ xl, const float* __restrict__ xr,
          const int* __restrict__ rowptr, const int* __restrict__ ssrc,
          const float* __restrict__ att, const float* __restrict__ b,
          __half* __restrict__ h)
{
    const int w = (blockIdx.x * blockDim.x + threadIdx.x) >> 6;
    if (w >= N_NODES) return;
    const int lane = threadIdx.x & 63;
    const int ch = lane * 4;

    const float4 at = *(const float4*)(att + ch);
    const float4 bb = *(const float4*)(b + ch);
    const float4 r  = *(const float4*)(xr + (size_t)w * 256 + ch);

    float4 a = make_float4(0.f, 0.f, 0.f, 0.f);
    float den = 0.f;

    const int beg = rowptr[w], end = rowptr[w + 1];
    for (int i = beg; i < end; ++i) {
        const int s = ssrc[i];
        union { uint2 u; __half2 h2[2]; } U;
        U.u = *(const uint2*)(xl + (size_t)s * 256 + ch);
        const float2 p01 = __half22float2(U.h2[0]);
        const float2 p23 = __half22float2(U.h2[1]);

        float m = leaky(p01.x + r.x) * at.x
                + leaky(p01.y + r.y) * at.y
                + leaky(p23.x + r.z) * at.z
                + leaky(p23.y + r.w) * at.w;
        m += __shfl_xor(m, 1, 64);
        m += __shfl_xor(m, 2, 64);
        m += __shfl_xor(m, 4, 64);
        m += __shfl_xor(m, 8, 64);
        const float e = __expf(m);
        a.x += e * p01.x; a.y += e * p01.y;
        a.z += e * p23.x; a.w += e * p23.y;
        den += e;
    }

    const float inv = 1.f / (den + EPS);
    float v0 = a.x * inv + bb.x;
    float v1 = a.y * inv + bb.y;
    float v2 = a.z * inv + bb.z;
    float v3 = a.w * inv + bb.w;
    v0 = v0 > 0.f ? v0 : __expf(v0) - 1.f;
    v1 = v1 > 0.f ? v1 : __expf(v1) - 1.f;
    v2 = v2 > 0.f ? v2 : __expf(v2) - 1.f;
    v3 = v3 > 0.f ? v3 : __expf(v3) - 1.f;
    union { uint2 u; __half2 h2[2]; } O;
    O.h2[0] = __floats2half2_rn(v0, v1);
    O.h2[1] = __floats2half2_rn(v2, v3);
    *(uint2*)(h + (size_t)w * 256 + ch) = O.u;
}

// ---------------------------------------------------------------------------
// Layer-2 aggregation (H=1, C=128). Two 32-lane halves, two edges per iter;
// xl fp16 gather. Cross-half combine at end; writes final fp32 output.
// ---------------------------------------------------------------------------
__global__ __launch_bounds__(256)
void agg2(const __half* __restrict__ xl, const float* __restrict__ xr,
          const int* __restrict__ rowptr, const int* __restrict__ ssrc,
          const float* __restrict__ att, const float* __restrict__ b,
          float* __restrict__ out)
{
    const int w = (blockIdx.x * blockDim.x + threadIdx.x) >> 6;
    if (w >= N_NODES) return;
    const int lane = threadIdx.x & 63;
    const int half = lane >> 5;
    const int ch = (lane & 31) * 4;

    const float4 at = *(const float4*)(att + ch);
    const float4 bb = *(const float4*)(b + ch);
    const float4 r  = *(const float4*)(xr + (size_t)w * 128 + ch);

    float4 a = make_float4(0.f, 0.f, 0.f, 0.f);
    float den = 0.f;

    const int beg = rowptr[w], end = rowptr[w + 1];
    for (int i = beg + half; i < end; i += 2) {
        const int s = ssrc[i];
        union { uint2 u; __half2 h2[2]; } U;
        U.u = *(const uint2*)(xl + (size_t)s * 128 + ch);
        const float2 p01 = __half22float2(U.h2[0]);
        const float2 p23 = __half22float2(U.h2[1]);

        float m = leaky(p01.x + r.x) * at.x
                + leaky(p01.y + r.y) * at.y
                + leaky(p23.x + r.z) * at.z
                + leaky(p23.y + r.w) * at.w;
        m += __shfl_xor(m, 1, 64);
        m += __shfl_xor(m, 2, 64);
        m += __shfl_xor(m, 4, 64);
        m += __shfl_xor(m, 8, 64);
        m += __shfl_xor(m, 16, 64);
        const float e = __expf(m);
        a.x += e * p01.x; a.y += e * p01.y;
        a.z += e * p23.x; a.w += e * p23.y;
        den += e;
    }

    a.x += __shfl_xor(a.x, 32, 64);
    a.y += __shfl_xor(a.y, 32, 64);
    a.z += __shfl_xor(a.z, 32, 64);
    a.w += __shfl_xor(a.w, 32, 64);
    den += __shfl_xor(den, 32, 64);

    if (half == 0) {
        const float inv = 1.f / (den + EPS);
        float4 o;
        o.x = a.x * inv + bb.x;
        o.y = a.y * inv + bb.y;
        o.z = a.z * inv + bb.z;
        o.w = a.w * inv + bb.w;
        *(float4*)(out + (size_t)w * 128 + ch) = o;
    }
}

extern "C" void kernel_launch(void* const* d_in, const int* in_sizes, int n_in,
                              void* d_out, int out_size, void* d_ws, size_t ws_size,
                              hipStream_t stream)
{
    const float* x    = (const float*)d_in[0];
    const int*   ei   = (const int*)d_in[1];
    const float* Wl1  = (const float*)d_in[2];
    const float* Wr1  = (const float*)d_in[3];
    const float* att1 = (const float*)d_in[4];
    const float* b1   = (const float*)d_in[5];
    const float* Wl2  = (const float*)d_in[6];
    const float* Wr2  = (const float*)d_in[7];
    const float* att2 = (const float*)d_in[8];
    const float* b2   = (const float*)d_in[9];
    const int* src = ei;
    const int* dst = ei + E_EDGES;
    float* out = (float*)d_out;

    // Workspace layout:
    //   xh    fp16 [N*128]             (x cast)
    //   xl1h  fp16 [N*256]             (reused as xl2h [N*128])
    //   xr1   fp32 [N*256]             (reused as xr2  [N*128])
    //   hh    fp16 [N*256]             (layer-1 output, fp16 for MFMA)
    //   W1t   fp16 [512*128]           (Wl1^T ; Wr1^T)
    //   W2t   fp16 [256*256]           (Wl2^T ; Wr2^T)
    //   ints: rowptr[N+1], cursor[N], deg[N], ssrc[E], locpre[N], blockSum[NB]
    __half* xh   = (__half*)d_ws;
    __half* xl1h = xh + (size_t)N_NODES * 128;
    float*  xr1  = (float*)(xl1h + (size_t)N_NODES * 256);
    __half* hh   = (__half*)(xr1 + (size_t)N_NODES * 256);
    __half* W1t  = hh + (size_t)N_NODES * 256;
    __half* W2t  = W1t + 512 * 128;
    int* rowptr   = (int*)(W2t + 256 * 256);
    int* cursor   = rowptr + (N_NODES + 1);
    int* deg      = cursor + N_NODES;
    int* ssrc     = deg + N_NODES;
    int* locpre   = ssrc + E_EDGES;
    int* blockSum = locpre + N_NODES;
    __half* xl2h = xl1h;
    float*  xr2  = xr1;

    const dim3 blk(256);
    const int gemm_gx = (N_NODES + 127) / 128;   // 391

    // --- converts ---
    cvt_x<<<(N_NODES * 128 / 4 + 255) / 256, blk, 0, stream>>>(x, xh, N_NODES * 128 / 4);
    cvt_wpair<<<(2 * 256 * 128 + 255) / 256, blk, 0, stream>>>(Wl1, Wr1, W1t, 128, 256);
    cvt_wpair<<<(2 * 128 * 256 + 255) / 256, blk, 0, stream>>>(Wl2, Wr2, W2t, 256, 128);

    // --- CSR build ---
    hipMemsetAsync(deg, 0, N_NODES * sizeof(int), stream);
    hist_dst<<<(E_EDGES + 255) / 256, blk, 0, stream>>>(dst, deg, E_EDGES);
    scan_local<<<NB_SCAN, blk, 0, stream>>>(deg, locpre, blockSum);
    scan_final<<<NB_SCAN, blk, 0, stream>>>(locpre, blockSum, rowptr, cursor);
    scatter_edges<<<(E_EDGES + 255) / 256, blk, 0, stream>>>(src, dst, cursor, ssrc, E_EDGES);

    // --- Layer 1: [N,128] @ [128,256] via fp16 MFMA ---
    gemm_mfma<__half><<<dim3(gemm_gx, 2), blk, 0, stream>>>(xh, W1t, xl1h, N_NODES, 128, 256);
    gemm_mfma<float ><<<dim3(gemm_gx, 2), blk, 0, stream>>>(xh, W1t + 256 * 128, xr1, N_NODES, 128, 256);
    agg1<<<(N_NODES * 64 + 255) / 256, blk, 0, stream>>>(xl1h, xr1, rowptr, ssrc, att1, b1, hh);

    // --- Layer 2: [N,256] @ [256,128] via fp16 MFMA ---
    gemm_mfma<__half><<<dim3(gemm_gx, 1), blk, 0, stream>>>(hh, W2t, xl2h, N_NODES, 256, 128);
    gemm_mfma<float ><<<dim3(gemm_gx, 1), blk, 0, stream>>>(hh, W2t + 128 * 256, xr2, N_NODES, 256, 128);
    agg2<<<(N_NODES * 64 + 255) / 256, blk, 0, stream>>>(xl2h, xr2, rowptr, ssrc, att2, b2, out);
}

// Round 7
// 361.744 us; speedup vs baseline: 3.9605x; 1.1716x over previous
//
#include <hip/hip_runtime.h>
#include <hip/hip_bf16.h>
#include <hip/hip_fp16.h>
#include <math.h>

#define N_NODES 50000
#define E_EDGES 800000
#define NEG_SLOPE 0.2f
#define EPS 1e-16f
#define NB_SCAN ((N_NODES + 255) / 256)   // 196

typedef _Float16 f16x8 __attribute__((ext_vector_type(8)));
typedef float    f32x4 __attribute__((ext_vector_type(4)));

__device__ __forceinline__ float leaky(float v) {
    return v > 0.f ? v : NEG_SLOPE * v;
}

// load 8 contiguous elements as f16x8, converting if input is fp32
__device__ __forceinline__ f16x8 load8(const float* p) {
    const float4 v0 = *(const float4*)p;
    const float4 v1 = *(const float4*)(p + 4);
    f16x8 r;
    r[0] = (_Float16)v0.x; r[1] = (_Float16)v0.y;
    r[2] = (_Float16)v0.z; r[3] = (_Float16)v0.w;
    r[4] = (_Float16)v1.x; r[5] = (_Float16)v1.y;
    r[6] = (_Float16)v1.z; r[7] = (_Float16)v1.w;
    return r;
}
__device__ __forceinline__ f16x8 load8(const _Float16* p) {
    return *(const f16x8*)p;
}

// ---------------------------------------------------------------------------
// MFMA GEMM (fp16 compute, fp32 accum): Y[N, M2] = X[N,K] @ Wt[M2,K]^T,
// fp16 output. X is fp32 (converted during staging) or fp16, templated.
// 128x128 tile, BK=32, 256 threads = 4 waves (2x2), each wave 64x64 =
// 4x4 tiles of v_mfma_f32_16x16x32_f16.
// A-frag: lane reads As[m=lane&15][k=(lane>>4)*8..+7]; B symmetric.
// C/D: col=lane&15, row=(lane>>4)*4+reg. LDS rows padded to 40 halves.
// ---------------------------------------------------------------------------
template <typename IT>
__global__ __launch_bounds__(256)
void gemm_mfma(const IT* __restrict__ X, const __half* __restrict__ Wth,
               __half* __restrict__ Y, int Nrows, int K, int M2)
{
    const _Float16* Wt = (const _Float16*)Wth;
    __shared__ _Float16 As[128][40];
    __shared__ _Float16 Bs[128][40];
    const int tid  = threadIdx.x;
    const int row0 = blockIdx.x * 128;
    const int col0 = blockIdx.y * 128;
    const int lane = tid & 63;
    const int wv   = tid >> 6;
    const int wr   = (wv >> 1) * 64;
    const int wc   = (wv & 1) * 64;
    const int fm   = lane & 15;
    const int fk   = (lane >> 4) * 8;
    const int quad = lane >> 4;

    f32x4 acc[4][4] = {};

    for (int k0 = 0; k0 < K; k0 += 32) {
        #pragma unroll
        for (int p = 0; p < 2; ++p) {
            const int idx = tid + p * 256;       // 0..511
            const int r = idx >> 2;
            const int c = (idx & 3) * 8;
            const int gr = row0 + r;
            f16x8 v = {};
            if (gr < Nrows)
                v = load8(X + (size_t)gr * K + k0 + c);
            *(f16x8*)&As[r][c] = v;
            *(f16x8*)&Bs[r][c] = *(const f16x8*)(Wt + (size_t)(col0 + r) * K + k0 + c);
        }
        __syncthreads();

        f16x8 af[4], bf[4];
        #pragma unroll
        for (int i = 0; i < 4; ++i) {
            af[i] = *(const f16x8*)&As[wr + i * 16 + fm][fk];
            bf[i] = *(const f16x8*)&Bs[wc + i * 16 + fm][fk];
        }
        #pragma unroll
        for (int i = 0; i < 4; ++i)
            #pragma unroll
            for (int j = 0; j < 4; ++j)
                acc[i][j] = __builtin_amdgcn_mfma_f32_16x16x32_f16(af[i], bf[j], acc[i][j], 0, 0, 0);
        __syncthreads();
    }

    #pragma unroll
    for (int i = 0; i < 4; ++i) {
        #pragma unroll
        for (int j = 0; j < 4; ++j) {
            const int col = col0 + wc + j * 16 + fm;
            #pragma unroll
            for (int rg = 0; rg < 4; ++rg) {
                const int row = row0 + wr + i * 16 + quad * 4 + rg;
                if (row < Nrows)
                    Y[(size_t)row * M2 + col] = __float2half(acc[i][j][rg]);
            }
        }
    }
}

// weights fp32 [K,M] pair -> fp16 [2M,K] transposed (Wa^T stacked on Wb^T)
__global__ __launch_bounds__(256)
void cvt_wpair(const float* __restrict__ Wa, const float* __restrict__ Wb,
               __half* __restrict__ Wt, int K, int M)
{
    const int id = blockIdx.x * 256 + threadIdx.x;
    if (id >= 2 * M * K) return;
    const int n = id / K, k = id - n * K;
    const float* W = (n < M) ? Wa : Wb;
    const int nn = (n < M) ? n : n - M;
    Wt[id] = __float2half(W[(size_t)k * M + nn]);
}

// ---------------------------------------------------------------------------
// CSR build: histogram -> two-phase parallel scan -> scatter.
// ---------------------------------------------------------------------------
__global__ __launch_bounds__(256)
void hist_dst(const int* __restrict__ dst, int* __restrict__ deg, int E)
{
    int i = blockIdx.x * blockDim.x + threadIdx.x;
    if (i < E) atomicAdd(&deg[dst[i]], 1);
}

__global__ __launch_bounds__(256)
void scan_local(const int* __restrict__ deg, int* __restrict__ locpre,
                int* __restrict__ blockSum)
{
    const int i = blockIdx.x * 256 + threadIdx.x;
    const int lane = threadIdx.x & 63;
    const int wid = threadIdx.x >> 6;
    const int val = (i < N_NODES) ? deg[i] : 0;

    int v = val;
    #pragma unroll
    for (int off = 1; off < 64; off <<= 1) {
        int t = __shfl_up(v, off, 64);
        if (lane >= off) v += t;
    }
    __shared__ int ws[4];
    if (lane == 63) ws[wid] = v;
    __syncthreads();
    int woff = 0;
    for (int k = 0; k < wid; ++k) woff += ws[k];
    if (i < N_NODES) locpre[i] = woff + v - val;
    if (threadIdx.x == 255) blockSum[blockIdx.x] = woff + v;
}

__global__ __launch_bounds__(256)
void scan_final(const int* __restrict__ locpre, const int* __restrict__ blockSum,
                int* __restrict__ rowptr, int* __restrict__ cursor)
{
    const int b = blockIdx.x;
    const int t = threadIdx.x;
    int v = (t < b) ? blockSum[t] : 0;          // NB_SCAN(=196) < 256
    #pragma unroll
    for (int off = 32; off; off >>= 1) v += __shfl_xor(v, off, 64);
    __shared__ int ws[4];
    if ((t & 63) == 0) ws[t >> 6] = v;
    __syncthreads();
    const int offset = ws[0] + ws[1] + ws[2] + ws[3];

    const int i = b * 256 + t;
    if (i < N_NODES) {
        const int rp = locpre[i] + offset;
        rowptr[i] = rp;
        cursor[i] = rp;
    }
    if (b == 0 && t == 0) rowptr[N_NODES] = E_EDGES;
}

__global__ __launch_bounds__(256)
void scatter_edges(const int* __restrict__ src, const int* __restrict__ dst,
                   int* __restrict__ cursor, int* __restrict__ ssrc, int E)
{
    int i = blockIdx.x * blockDim.x + threadIdx.x;
    if (i < E) {
        int pos = atomicAdd(&cursor[dst[i]], 1);
        ssrc[pos] = src[i];
    }
}

// ---------------------------------------------------------------------------
// Layer-1 aggregation (H=4, C=64). One wave per dst node; lane owns 4 ch.
// xlr fp16 [N,512] = [xl | xr]. 4-edge unroll: 4 gathers issued up-front,
// butterflies interleaved level-by-level to overlap DS latency.
// ---------------------------------------------------------------------------
__global__ __launch_bounds__(256)
void agg1(const __half* __restrict__ xlr, const int* __restrict__ rowptr,
          const int* __restrict__ ssrc, const float* __restrict__ att,
          const float* __restrict__ b, __half* __restrict__ h)
{
    const int w = (blockIdx.x * blockDim.x + threadIdx.x) >> 6;
    if (w >= N_NODES) return;
    const int lane = threadIdx.x & 63;
    const int ch = lane * 4;

    const float4 at = *(const float4*)(att + ch);
    const float4 bb = *(const float4*)(b + ch);
    union { uint2 u; __half2 h2[2]; } R;
    R.u = *(const uint2*)(xlr + (size_t)w * 512 + 256 + ch);
    const float2 r01 = __half22float2(R.h2[0]);
    const float2 r23 = __half22float2(R.h2[1]);

    float4 a = make_float4(0.f, 0.f, 0.f, 0.f);
    float den = 0.f;

    const int beg = rowptr[w], end = rowptr[w + 1];
    int i = beg;
    while (i + 4 <= end) {
        uint2 u[4];
        #pragma unroll
        for (int j = 0; j < 4; ++j) {
            const int s = ssrc[i + j];
            u[j] = *(const uint2*)(xlr + (size_t)s * 512 + ch);
        }
        float2 p01[4], p23[4];
        float m[4];
        #pragma unroll
        for (int j = 0; j < 4; ++j) {
            union { uint2 uu; __half2 h2[2]; } U; U.uu = u[j];
            p01[j] = __half22float2(U.h2[0]);
            p23[j] = __half22float2(U.h2[1]);
            m[j] = leaky(p01[j].x + r01.x) * at.x
                 + leaky(p01[j].y + r01.y) * at.y
                 + leaky(p23[j].x + r23.x) * at.z
                 + leaky(p23[j].y + r23.y) * at.w;
        }
        #pragma unroll
        for (int off = 1; off < 16; off <<= 1)
            #pragma unroll
            for (int j = 0; j < 4; ++j)
                m[j] += __shfl_xor(m[j], off, 64);
        #pragma unroll
        for (int j = 0; j < 4; ++j) {
            const float e = __expf(m[j]);
            a.x += e * p01[j].x; a.y += e * p01[j].y;
            a.z += e * p23[j].x; a.w += e * p23[j].y;
            den += e;
        }
        i += 4;
    }
    while (i < end) {
        const int s = ssrc[i];
        union { uint2 uu; __half2 h2[2]; } U;
        U.uu = *(const uint2*)(xlr + (size_t)s * 512 + ch);
        const float2 p01 = __half22float2(U.h2[0]);
        const float2 p23 = __half22float2(U.h2[1]);
        float m = leaky(p01.x + r01.x) * at.x
                + leaky(p01.y + r01.y) * at.y
                + leaky(p23.x + r23.x) * at.z
                + leaky(p23.y + r23.y) * at.w;
        m += __shfl_xor(m, 1, 64);
        m += __shfl_xor(m, 2, 64);
        m += __shfl_xor(m, 4, 64);
        m += __shfl_xor(m, 8, 64);
        const float e = __expf(m);
        a.x += e * p01.x; a.y += e * p01.y;
        a.z += e * p23.x; a.w += e * p23.y;
        den += e;
        ++i;
    }

    const float inv = 1.f / (den + EPS);
    float v0 = a.x * inv + bb.x;
    float v1 = a.y * inv + bb.y;
    float v2 = a.z * inv + bb.z;
    float v3 = a.w * inv + bb.w;
    v0 = v0 > 0.f ? v0 : __expf(v0) - 1.f;
    v1 = v1 > 0.f ? v1 : __expf(v1) - 1.f;
    v2 = v2 > 0.f ? v2 : __expf(v2) - 1.f;
    v3 = v3 > 0.f ? v3 : __expf(v3) - 1.f;
    union { uint2 u; __half2 h2[2]; } O;
    O.h2[0] = __floats2half2_rn(v0, v1);
    O.h2[1] = __floats2half2_rn(v2, v3);
    *(uint2*)(h + (size_t)w * 256 + ch) = O.u;
}

// ---------------------------------------------------------------------------
// Layer-2 aggregation (H=1, C=128). xlr fp16 [N,256] = [xl | xr]. Two 32-lane
// halves, each unrolled 2 edges -> 4 gathers in flight per wave.
// ---------------------------------------------------------------------------
__global__ __launch_bounds__(256)
void agg2(const __half* __restrict__ xlr, const int* __restrict__ rowptr,
          const int* __restrict__ ssrc, const float* __restrict__ att,
          const float* __restrict__ b, float* __restrict__ out)
{
    const int w = (blockIdx.x * blockDim.x + threadIdx.x) >> 6;
    if (w >= N_NODES) return;
    const int lane = threadIdx.x & 63;
    const int half = lane >> 5;
    const int ch = (lane & 31) * 4;

    const float4 at = *(const float4*)(att + ch);
    const float4 bb = *(const float4*)(b + ch);
    union { uint2 u; __half2 h2[2]; } R;
    R.u = *(const uint2*)(xlr + (size_t)w * 256 + 128 + ch);
    const float2 r01 = __half22float2(R.h2[0]);
    const float2 r23 = __half22float2(R.h2[1]);

    float4 a = make_float4(0.f, 0.f, 0.f, 0.f);
    float den = 0.f;

    const int beg = rowptr[w], end = rowptr[w + 1];
    int i = beg + half;
    while (i + 2 < end) {          // edges i and i+2 both valid
        uint2 u[2];
        #pragma unroll
        for (int j = 0; j < 2; ++j) {
            const int s = ssrc[i + 2 * j];
            u[j] = *(const uint2*)(xlr + (size_t)s * 256 + ch);
        }
        float2 p01[2], p23[2];
        float m[2];
        #pragma unroll
        for (int j = 0; j < 2; ++j) {
            union { uint2 uu; __half2 h2[2]; } U; U.uu = u[j];
            p01[j] = __half22float2(U.h2[0]);
            p23[j] = __half22float2(U.h2[1]);
            m[j] = leaky(p01[j].x + r01.x) * at.x
                 + leaky(p01[j].y + r01.y) * at.y
                 + leaky(p23[j].x + r23.x) * at.z
                 + leaky(p23[j].y + r23.y) * at.w;
        }
        #pragma unroll
        for (int off = 1; off < 32; off <<= 1)
            #pragma unroll
            for (int j = 0; j < 2; ++j)
                m[j] += __shfl_xor(m[j], off, 64);
        #pragma unroll
        for (int j = 0; j < 2; ++j) {
            const float e = __expf(m[j]);
            a.x += e * p01[j].x; a.y += e * p01[j].y;
            a.z += e * p23[j].x; a.w += e * p23[j].y;
            den += e;
        }
        i += 4;
    }
    if (i < end) {
        const int s = ssrc[i];
        union { uint2 uu; __half2 h2[2]; } U;
        U.uu = *(const uint2*)(xlr + (size_t)s * 256 + ch);
        const float2 p01 = __half22float2(U.h2[0]);
        const float2 p23 = __half22float2(U.h2[1]);
        float m = leaky(p01.x + r01.x) * at.x
                + leaky(p01.y + r01.y) * at.y
                + leaky(p23.x + r23.x) * at.z
                + leaky(p23.y + r23.y) * at.w;
        #pragma unroll
        for (int off = 1; off < 32; off <<= 1)
            m += __shfl_xor(m, off, 64);
        const float e = __expf(m);
        a.x += e * p01.x; a.y += e * p01.y;
        a.z += e * p23.x; a.w += e * p23.y;
        den += e;
    }

    a.x += __shfl_xor(a.x, 32, 64);
    a.y += __shfl_xor(a.y, 32, 64);
    a.z += __shfl_xor(a.z, 32, 64);
    a.w += __shfl_xor(a.w, 32, 64);
    den += __shfl_xor(den, 32, 64);

    if (half == 0) {
        const float inv = 1.f / (den + EPS);
        float4 o;
        o.x = a.x * inv + bb.x;
        o.y = a.y * inv + bb.y;
        o.z = a.z * inv + bb.z;
        o.w = a.w * inv + bb.w;
        *(float4*)(out + (size_t)w * 128 + ch) = o;
    }
}

extern "C" void kernel_launch(void* const* d_in, const int* in_sizes, int n_in,
                              void* d_out, int out_size, void* d_ws, size_t ws_size,
                              hipStream_t stream)
{
    const float* x    = (const float*)d_in[0];
    const int*   ei   = (const int*)d_in[1];
    const float* Wl1  = (const float*)d_in[2];
    const float* Wr1  = (const float*)d_in[3];
    const float* att1 = (const float*)d_in[4];
    const float* b1   = (const float*)d_in[5];
    const float* Wl2  = (const float*)d_in[6];
    const float* Wr2  = (const float*)d_in[7];
    const float* att2 = (const float*)d_in[8];
    const float* b2   = (const float*)d_in[9];
    const int* src = ei;
    const int* dst = ei + E_EDGES;
    float* out = (float*)d_out;

    // Workspace layout (fp16 unless noted):
    //   xlr1 [N,512] = [xl1|xr1]   (51.2 MB)
    //   hh   [N,256]               (layer-1 ELU output)
    //   xlr2 [N,256] = [xl2|xr2]   (overlays xlr1 — dead after agg1)
    //   W1t  [512,128], W2t [256,256]
    //   ints: rowptr[N+1], cursor[N], deg[N], ssrc[E], locpre[N], blockSum[NB]
    __half* xlr1 = (__half*)d_ws;
    __half* hh   = xlr1 + (size_t)N_NODES * 512;
    __half* W1t  = hh + (size_t)N_NODES * 256;
    __half* W2t  = W1t + 512 * 128;
    int* rowptr   = (int*)(W2t + 256 * 256);
    int* cursor   = rowptr + (N_NODES + 1);
    int* deg      = cursor + N_NODES;
    int* ssrc     = deg + N_NODES;
    int* locpre   = ssrc + E_EDGES;
    int* blockSum = locpre + N_NODES;
    __half* xlr2 = xlr1;

    const dim3 blk(256);
    const int gemm_gx = (N_NODES + 127) / 128;   // 391

    // --- weight converts ---
    cvt_wpair<<<(2 * 256 * 128 + 255) / 256, blk, 0, stream>>>(Wl1, Wr1, W1t, 128, 256);
    cvt_wpair<<<(2 * 128 * 256 + 255) / 256, blk, 0, stream>>>(Wl2, Wr2, W2t, 256, 128);

    // --- CSR build ---
    hipMemsetAsync(deg, 0, N_NODES * sizeof(int), stream);
    hist_dst<<<(E_EDGES + 255) / 256, blk, 0, stream>>>(dst, deg, E_EDGES);
    scan_local<<<NB_SCAN, blk, 0, stream>>>(deg, locpre, blockSum);
    scan_final<<<NB_SCAN, blk, 0, stream>>>(locpre, blockSum, rowptr, cursor);
    scatter_edges<<<(E_EDGES + 255) / 256, blk, 0, stream>>>(src, dst, cursor, ssrc, E_EDGES);

    // --- Layer 1: [N,128] @ [128,512] (fused Wl|Wr), fp32 input converted in staging ---
    gemm_mfma<float><<<dim3(gemm_gx, 4), blk, 0, stream>>>(x, W1t, xlr1, N_NODES, 128, 512);
    agg1<<<(N_NODES * 64 + 255) / 256, blk, 0, stream>>>(xlr1, rowptr, ssrc, att1, b1, hh);

    // --- Layer 2: [N,256] @ [256,256] (fused Wl|Wr) ---
    gemm_mfma<_Float16><<<dim3(gemm_gx, 2), blk, 0, stream>>>((const _Float16*)hh, W2t, xlr2, N_NODES, 256, 256);
    agg2<<<(N_NODES * 64 + 255) / 256, blk, 0, stream>>>(xlr2, rowptr, ssrc, att2, b2, out);
}